// Round 1
// baseline (4891.649 us; speedup 1.0000x reference)
//
#include <hip/hip_runtime.h>
#include <math.h>

// ---------------- problem constants ----------------
#define NLAY 120         // LSTM layers
#define TT   1016        // LSTM time steps (1024 - 4 - 4)
#define RW   64          // ring slots per chain (power of 2)
#define BPW  32          // backpressure window (< RW with margin -> cache-lap safety)
#define TPB  384         // threads per LSTM block = 32 batch x 12 hidden
#define HEADN (64 * 120) // rows for the head MLP

typedef float v2f __attribute__((ext_vector_type(2)));

__device__ __forceinline__ float fast_rcp(float x) { return __builtin_amdgcn_rcpf(x); }
__device__ __forceinline__ float fast_sig(float x) { return fast_rcp(1.f + __expf(-x)); }
__device__ __forceinline__ float fast_tanh(float x) { return 1.f - 2.f * fast_rcp(1.f + __expf(2.f * x)); }

__device__ __forceinline__ int poll_ge_acq(const int* p, int target, int cur) {
  long g = 0;
  while (cur < target) {
    cur = __hip_atomic_load(p, __ATOMIC_ACQUIRE, __HIP_MEMORY_SCOPE_AGENT);
    if (++g > 20000000L) break;   // watchdog: fail loud (wrong answer), never hang
  }
  return cur;
}
__device__ __forceinline__ int poll_ge_rlx(const int* p, int target, int cur) {
  long g = 0;
  while (cur < target) {
    cur = __hip_atomic_load(p, __ATOMIC_RELAXED, __HIP_MEMORY_SCOPE_AGENT);
    if (++g > 20000000L) break;
  }
  return cur;
}

// ---------------- conv1d(6->6,K=5,valid) + bias, accumulate BN stats ----------------
// optional input transform: v = relu(scale[ci]*v + shift[ci])  (fuses BN1+ReLU into conv2)
__global__ void k_conv(const float* __restrict__ xin, const float* __restrict__ cw,
                       const float* __restrict__ cb, const float* __restrict__ aff,
                       float* __restrict__ yout, float* __restrict__ stat,
                       int Tin, int Tout, int use_aff)
{
  const int bx = blockIdx.x;            // 0..383 : b*6+co
  const int b = bx / 6, co = bx - b * 6;
  const int tid = threadIdx.x;          // 256
  __shared__ float wsh[30];
  __shared__ float ssh[6], shsh[6];
  if (tid < 30) wsh[tid] = cw[co * 30 + tid];
  if (tid < 6) {
    ssh[tid]  = use_aff ? aff[tid] : 1.f;
    shsh[tid] = use_aff ? aff[6 + tid] : 0.f;
  }
  __syncthreads();
  const float bias = cb[co];
  float lsum = 0.f, lsq = 0.f;
  for (int t = tid; t < Tout; t += 256) {
    float acc = bias;
#pragma unroll
    for (int ci = 0; ci < 6; ++ci) {
      const float* xr = xin + ((size_t)b * 6 + ci) * Tin + t;
      const float s = ssh[ci], sh = shsh[ci];
#pragma unroll
      for (int k = 0; k < 5; ++k) {
        float v = xr[k];
        if (use_aff) v = fmaxf(fmaf(s, v, sh), 0.f);
        acc += wsh[ci * 5 + k] * v;
      }
    }
    yout[((size_t)b * 6 + co) * Tout + t] = acc;
    lsum += acc; lsq += acc * acc;
  }
  __shared__ float rs[256], rq[256];
  rs[tid] = lsum; rq[tid] = lsq;
  __syncthreads();
  for (int s = 128; s > 0; s >>= 1) {
    if (tid < s) { rs[tid] += rs[tid + s]; rq[tid] += rq[tid + s]; }
    __syncthreads();
  }
  if (tid == 0) { atomicAdd(&stat[co], rs[0]); atomicAdd(&stat[6 + co], rq[0]); }
}

// ---------------- finalize BN: stats -> per-channel scale/shift ----------------
__global__ void k_finalize(const float* __restrict__ stat,
                           const float* __restrict__ gamma, const float* __restrict__ beta,
                           float* __restrict__ aff, float invN)
{
  const int c = threadIdx.x;
  if (c < 6) {
    float mean = stat[c] * invN;
    float var  = stat[6 + c] * invN - mean * mean;
    float sc   = gamma[c] * rsqrtf(var + 1e-5f);
    aff[c]     = sc;
    aff[6 + c] = fmaf(-mean, sc, beta[c]);
  }
}

// ---------------- BN2+ReLU + attn projection (6->12) + ReLU; write seq0[t][b*12+j] ----------------
__global__ void k_attn(const float* __restrict__ y2, const float* __restrict__ aff2,
                       const float* __restrict__ aw, const float* __restrict__ ab,
                       float* __restrict__ seq0)
{
  const int t = blockIdx.x;             // 0..1015
  const int tid = threadIdx.x;          // 0..767
  __shared__ float zb[6 * 64];
  if (tid < 384) {
    const int c = tid >> 6, bb = tid & 63;
    float v = y2[((size_t)bb * 6 + c) * TT + t];
    zb[c * 64 + bb] = fmaxf(fmaf(aff2[c], v, aff2[6 + c]), 0.f);
  }
  __syncthreads();
  const int b = tid / 12, j = tid - b * 12;
  float acc = ab[j];
#pragma unroll
  for (int c = 0; c < 6; ++c) acc += aw[j * 6 + c] * zb[c * 64 + b];
  seq0[(size_t)t * 768 + tid] = fmaxf(acc, 0.f);
}

// ---------------- 120-layer LSTM, pipelined producer->consumer chains ----------------
// grid = 240 blocks: chain bid = layer*2 + batch-half. 384 thr = 32 b x 12 j.
// thread (b,j) owns c[b][j] + all 96 gate weights in VGPRs; h exchanged via LDS;
// cross-layer hand-off: sc1 (agent) ring stores + acquire-polled progress flags.
__global__ __launch_bounds__(TPB, 2) void k_lstm(
    const float* __restrict__ wih, const float* __restrict__ whh,
    const float* __restrict__ bih, const float* __restrict__ bhh,
    const float* __restrict__ seq0, float* __restrict__ ring,
    int* __restrict__ prog, int* __restrict__ cons,
    float* __restrict__ hfin)
{
  const int bid  = blockIdx.x;        // 0..239
  const int l    = bid >> 1;
  const int half = bid & 1;
  const int tid  = threadIdx.x;       // 0..383
  const int bl   = tid / 12;          // local batch 0..31
  const int j    = tid - bl * 12;     // hidden unit 0..11

  // weights as (i,f) and (g,o) float2 pairs -> v_pk_fma_f32
  const float* wi = wih + l * 576;
  const float* wh = whh + l * 576;
  v2f wx_if[12], wx_go[12], whf_if[12], whf_go[12];
#pragma unroll
  for (int k = 0; k < 12; ++k) {
    wx_if[k]  = (v2f){ wi[(j     ) * 12 + k], wi[(j + 12) * 12 + k] };
    wx_go[k]  = (v2f){ wi[(j + 24) * 12 + k], wi[(j + 36) * 12 + k] };
    whf_if[k] = (v2f){ wh[(j     ) * 12 + k], wh[(j + 12) * 12 + k] };
    whf_go[k] = (v2f){ wh[(j + 24) * 12 + k], wh[(j + 36) * 12 + k] };
  }
  const float* ba = bih + l * 48;
  const float* bb = bhh + l * 48;
  v2f b_if = (v2f){ ba[j]      + bb[j],      ba[j + 12] + bb[j + 12] };
  v2f b_go = (v2f){ ba[j + 24] + bb[j + 24], ba[j + 36] + bb[j + 36] };

  __shared__ __align__(16) float hs[2][TPB];
  hs[0][tid] = 0.f;
  float c = 0.f, hn = 0.f;
  __syncthreads();

  const float* rin = (l > 0) ? (ring + (size_t)(bid - 2) * (RW * TPB)) : seq0;
  float*       rout = ring + (size_t)bid * (RW * TPB);
  const int*   pin  = prog + ((l > 0) ? (bid - 2) : 0);
  int kp = 0, kc = 0;
  int ping = 0;

  // prologue: ensure slots 0,1 valid (l>0) and fetch x[0]
  float4 xA, xB, xC;
  if (l == 0) {
    const float4* p = (const float4*)(seq0 + half * TPB + bl * 12);
    xA = p[0]; xB = p[1]; xC = p[2];
  } else {
    kp = poll_ge_acq(pin, 2, kp);
    const float4* p = (const float4*)(rin + bl * 12);
    xA = p[0]; xB = p[1]; xC = p[2];
  }

  for (int t = 0; t < TT; ++t) {
    // prefetch x[t+1]; validity (kp >= t+2) was established one iteration ago
    float4 nA, nB, nC;
    if (t + 1 < TT) {
      if (l == 0) {
        const float4* p = (const float4*)(seq0 + (size_t)(t + 1) * 768 + half * TPB + bl * 12);
        nA = p[0]; nB = p[1]; nC = p[2];
      } else {
        const float4* p = (const float4*)(rin + ((t + 1) & (RW - 1)) * TPB + bl * 12);
        nA = p[0]; nB = p[1]; nC = p[2];
        int tgt = (t + 3 < TT) ? (t + 3) : TT;      // poll one step ahead (latency off critical path)
        kp = poll_ge_acq(pin, tgt, kp);
      }
    }
    // backpressure before overwriting ring slot t (window BPW < RW keeps cache laps safe)
    if (l < NLAY - 1 && t >= BPW) {
      kc = poll_ge_rlx(cons + (bid + 2), t - BPW + 1, kc);
    }

    // gates: g = Wih*x + Whh*h + b  (packed (i,f) and (g,o))
    const float4* h4 = (const float4*)(&hs[ping][bl * 12]);
    float4 hA = h4[0], hB = h4[1], hC = h4[2];
    float xv[12] = {xA.x,xA.y,xA.z,xA.w, xB.x,xB.y,xB.z,xB.w, xC.x,xC.y,xC.z,xC.w};
    float hv[12] = {hA.x,hA.y,hA.z,hA.w, hB.x,hB.y,hB.z,hB.w, hC.x,hC.y,hC.z,hC.w};
    v2f aif = b_if, ago = b_go;
#pragma unroll
    for (int k = 0; k < 12; ++k) {
      v2f xx = { xv[k], xv[k] };
      aif = __builtin_elementwise_fma(wx_if[k], xx, aif);
      ago = __builtin_elementwise_fma(wx_go[k], xx, ago);
    }
#pragma unroll
    for (int k = 0; k < 12; ++k) {
      v2f hh = { hv[k], hv[k] };
      aif = __builtin_elementwise_fma(whf_if[k], hh, aif);
      ago = __builtin_elementwise_fma(whf_go[k], hh, ago);
    }
    float ig = fast_sig(aif.x);
    float fg = fast_sig(aif.y);
    float gg = fast_tanh(ago.x);
    float og = fast_sig(ago.y);
    c  = fg * c + ig * gg;
    hn = og * fast_tanh(c);

    hs[ping ^ 1][tid] = hn;
    if (l < NLAY - 1)
      __hip_atomic_store(&rout[(t & (RW - 1)) * TPB + tid], hn,
                         __ATOMIC_RELAXED, __HIP_MEMORY_SCOPE_AGENT);  // sc1 -> coherent at L3
    __syncthreads();  // compiler emits s_waitcnt vmcnt(0) before s_barrier -> ring stores drained
    if (tid == 0) {
      if (l < NLAY - 1)
        __hip_atomic_store(&prog[bid], t + 1, __ATOMIC_RELAXED, __HIP_MEMORY_SCOPE_AGENT);
      if (l > 0 && (((t & 7) == 7) || t == TT - 1))
        __hip_atomic_store(&cons[bid], t + 1, __ATOMIC_RELAXED, __HIP_MEMORY_SCOPE_AGENT);
    }
    xA = nA; xB = nB; xC = nC;
    ping ^= 1;
  }
  hfin[l * 768 + half * TPB + tid] = hn;   // [l][b*12+j], b global
}

// ---------------- head: lin1+relu, lin2+relu, mu, softplus(sigma) ----------------
__global__ void k_head(const float* __restrict__ hfin,
                       const float* __restrict__ w1, const float* __restrict__ b1,
                       const float* __restrict__ w2, const float* __restrict__ b2,
                       const float* __restrict__ wm, const float* __restrict__ bm,
                       const float* __restrict__ wsg, const float* __restrict__ bsg,
                       float* __restrict__ out)
{
  const int tid = threadIdx.x;
  __shared__ float s1[144], s2[144], sm[144], ss[144];
  __shared__ float v1[12], v2[12], vm[12], vs[12];
  if (tid < 144) { s1[tid] = w1[tid]; s2[tid] = w2[tid]; sm[tid] = wm[tid]; ss[tid] = wsg[tid]; }
  if (tid < 12)  { v1[tid] = b1[tid]; v2[tid] = b2[tid]; vm[tid] = bm[tid]; vs[tid] = bsg[tid]; }
  __syncthreads();
  const int r = blockIdx.x * 256 + tid;   // 0..7679 = b*120 + l
  const int b = r / 120, l = r - b * 120;
  float h[12];
#pragma unroll
  for (int k = 0; k < 12; ++k) h[k] = hfin[l * 768 + b * 12 + k];
  float u1[12];
#pragma unroll
  for (int u = 0; u < 12; ++u) {
    float a = v1[u];
#pragma unroll
    for (int k = 0; k < 12; ++k) a += s1[u * 12 + k] * h[k];
    u1[u] = fmaxf(a, 0.f);
  }
  float u2[12];
#pragma unroll
  for (int u = 0; u < 12; ++u) {
    float a = v2[u];
#pragma unroll
    for (int k = 0; k < 12; ++k) a += s2[u * 12 + k] * u1[k];
    u2[u] = fmaxf(a, 0.f);
  }
  const size_t base = (size_t)r * 12;
#pragma unroll
  for (int u = 0; u < 12; ++u) out[base + u] = u2[u];
#pragma unroll
  for (int u = 0; u < 12; ++u) {
    float a = vm[u];
#pragma unroll
    for (int k = 0; k < 12; ++k) a += sm[u * 12 + k] * u2[k];
    out[92160 + base + u] = a;
  }
#pragma unroll
  for (int u = 0; u < 12; ++u) {
    float a = vs[u];
#pragma unroll
    for (int k = 0; k < 12; ++k) a += ss[u * 12 + k] * u2[k];
    // stable softplus = max(a,0) + log1p(exp(-|a|))
    out[184320 + base + u] = fmaxf(a, 0.f) + log1pf(expf(-fabsf(a)));
  }
}

// ---------------- launcher ----------------
extern "C" void kernel_launch(void* const* d_in, const int* in_sizes, int n_in,
                              void* d_out, int out_size, void* d_ws, size_t ws_size,
                              hipStream_t stream)
{
  const float* x   = (const float*)d_in[0];
  const float* c1w = (const float*)d_in[1];
  const float* c1b = (const float*)d_in[2];
  const float* g1  = (const float*)d_in[3];
  const float* be1 = (const float*)d_in[4];
  const float* c2w = (const float*)d_in[5];
  const float* c2b = (const float*)d_in[6];
  const float* g2  = (const float*)d_in[7];
  const float* be2 = (const float*)d_in[8];
  const float* aw  = (const float*)d_in[9];
  const float* ab  = (const float*)d_in[10];
  const float* wih = (const float*)d_in[11];
  const float* whh = (const float*)d_in[12];
  const float* bih = (const float*)d_in[13];
  const float* bhh = (const float*)d_in[14];
  const float* l1w = (const float*)d_in[15];
  const float* l1b = (const float*)d_in[16];
  const float* l2w = (const float*)d_in[17];
  const float* l2b = (const float*)d_in[18];
  const float* muw = (const float*)d_in[19];
  const float* mub = (const float*)d_in[20];
  const float* sgw = (const float*)d_in[21];
  const float* sgb = (const float*)d_in[22];

  float* ws    = (float*)d_ws;
  float* stat1 = ws;                    // 12
  float* stat2 = ws + 12;               // 12
  float* aff1  = ws + 24;               // 12 (scale[6], shift[6])
  float* aff2  = ws + 36;               // 12
  int*   prog  = (int*)(ws + 64);       // 240
  int*   cons  = (int*)(ws + 304);      // 240
  float* y1    = ws + 576;              // 64*6*1020
  float* y2    = y1 + 391680;           // 64*6*1016
  float* seq0  = y2 + 390144;           // 1016*768
  float* ring  = seq0 + 780288;         // 240*64*384
  float* hfin  = ring + (size_t)240 * RW * TPB; // 120*768

  hipMemsetAsync(d_ws, 0, 576 * sizeof(float), stream);  // zero stats + flags (ws is poisoned)

  k_conv<<<384, 256, 0, stream>>>(x, c1w, c1b, nullptr, y1, stat1, 1024, 1020, 0);
  k_finalize<<<1, 64, 0, stream>>>(stat1, g1, be1, aff1, 1.f / 65280.f);
  k_conv<<<384, 256, 0, stream>>>(y1, c2w, c2b, aff1, y2, stat2, 1020, 1016, 1);
  k_finalize<<<1, 64, 0, stream>>>(stat2, g2, be2, aff2, 1.f / 65024.f);
  k_attn<<<1016, 768, 0, stream>>>(y2, aff2, aw, ab, seq0);
  k_lstm<<<240, TPB, 0, stream>>>(wih, whh, bih, bhh, seq0, ring, prog, cons, hfin);
  k_head<<<30, 256, 0, stream>>>(hfin, l1w, l1b, l2w, l2b, muw, mub, sgw, sgb, (float*)d_out);
}

// Round 2
// 1515.129 us; speedup vs baseline: 3.2285x; 3.2285x over previous
//
#include <hip/hip_runtime.h>
#include <math.h>

// ---------------- problem constants ----------------
#define NLAY 120         // LSTM layers
#define TT   1016        // LSTM time steps (1024 - 4 - 4)
#define SEG  30          // layers per block
#define NSEG 4           // segments (blocks) per chain: 4*30 = 120
#define RW   64          // ring slots per hop (power of 2)
#define TPB  384         // threads per LSTM block: 30 layers x 12 hidden = 360 active

typedef float v2f __attribute__((ext_vector_type(2)));

__device__ __forceinline__ float fast_rcp(float x) { return __builtin_amdgcn_rcpf(x); }
__device__ __forceinline__ float fast_sig(float x) { return fast_rcp(1.f + __expf(-x)); }
__device__ __forceinline__ float fast_tanh(float x) { return 1.f - 2.f * fast_rcp(1.f + __expf(2.f * x)); }

// relaxed agent-scope poll: L1/L2-bypassing load, no invalidate side effects
__device__ __forceinline__ int poll_ge_rlx(const int* p, int target, int cur) {
  long g = 0;
  while (cur < target) {
    cur = __hip_atomic_load(p, __ATOMIC_RELAXED, __HIP_MEMORY_SCOPE_AGENT);
    if (++g > 50000000L) break;   // watchdog: fail loud (wrong answer), never hang
  }
  return cur;
}

// ---------------- conv1d(6->6,K=5,valid) + bias, accumulate BN stats ----------------
__global__ void k_conv(const float* __restrict__ xin, const float* __restrict__ cw,
                       const float* __restrict__ cb, const float* __restrict__ aff,
                       float* __restrict__ yout, float* __restrict__ stat,
                       int Tin, int Tout, int use_aff)
{
  const int bx = blockIdx.x;            // 0..383 : b*6+co
  const int b = bx / 6, co = bx - b * 6;
  const int tid = threadIdx.x;          // 256
  __shared__ float wsh[30];
  __shared__ float ssh[6], shsh[6];
  if (tid < 30) wsh[tid] = cw[co * 30 + tid];
  if (tid < 6) {
    ssh[tid]  = use_aff ? aff[tid] : 1.f;
    shsh[tid] = use_aff ? aff[6 + tid] : 0.f;
  }
  __syncthreads();
  const float bias = cb[co];
  float lsum = 0.f, lsq = 0.f;
  for (int t = tid; t < Tout; t += 256) {
    float acc = bias;
#pragma unroll
    for (int ci = 0; ci < 6; ++ci) {
      const float* xr = xin + ((size_t)b * 6 + ci) * Tin + t;
      const float s = ssh[ci], sh = shsh[ci];
#pragma unroll
      for (int k = 0; k < 5; ++k) {
        float v = xr[k];
        if (use_aff) v = fmaxf(fmaf(s, v, sh), 0.f);
        acc += wsh[ci * 5 + k] * v;
      }
    }
    yout[((size_t)b * 6 + co) * Tout + t] = acc;
    lsum += acc; lsq += acc * acc;
  }
  __shared__ float rs[256], rq[256];
  rs[tid] = lsum; rq[tid] = lsq;
  __syncthreads();
  for (int s = 128; s > 0; s >>= 1) {
    if (tid < s) { rs[tid] += rs[tid + s]; rq[tid] += rq[tid + s]; }
    __syncthreads();
  }
  if (tid == 0) { atomicAdd(&stat[co], rs[0]); atomicAdd(&stat[6 + co], rq[0]); }
}

// ---------------- finalize BN: stats -> per-channel scale/shift ----------------
__global__ void k_finalize(const float* __restrict__ stat,
                           const float* __restrict__ gamma, const float* __restrict__ beta,
                           float* __restrict__ aff, float invN)
{
  const int c = threadIdx.x;
  if (c < 6) {
    float mean = stat[c] * invN;
    float var  = stat[6 + c] * invN - mean * mean;
    float sc   = gamma[c] * rsqrtf(var + 1e-5f);
    aff[c]     = sc;
    aff[6 + c] = fmaf(-mean, sc, beta[c]);
  }
}

// ---------------- BN2+ReLU + attn projection (6->12) + ReLU; write seq0[t][b*12+j] ----------------
__global__ void k_attn(const float* __restrict__ y2, const float* __restrict__ aff2,
                       const float* __restrict__ aw, const float* __restrict__ ab,
                       float* __restrict__ seq0)
{
  const int t = blockIdx.x;             // 0..1015
  const int tid = threadIdx.x;          // 0..767
  __shared__ float zb[6 * 64];
  if (tid < 384) {
    const int c = tid >> 6, bb = tid & 63;
    float v = y2[((size_t)bb * 6 + c) * TT + t];
    zb[c * 64 + bb] = fmaxf(fmaf(aff2[c], v, aff2[6 + c]), 0.f);
  }
  __syncthreads();
  const int b = tid / 12, j = tid - b * 12;
  float acc = ab[j];
#pragma unroll
  for (int c = 0; c < 6; ++c) acc += aw[j * 6 + c] * zb[c * 64 + b];
  seq0[(size_t)t * 768 + tid] = fmaxf(acc, 0.f);
}

// ---------------- 120-layer LSTM: 30 layers per block, LDS wavefront pipeline ----------------
// grid = 256 blocks: bid = chain*4 + seg; chain = batch element (64), seg = layer group.
// thread (ll, j): layer seg*30+ll, hidden unit j. Diagonal schedule: at block-step s,
// layer ll computes t = s - ll. Hand-off between layers via double-buffered LDS (1 barrier
// per step); between segments via 64-slot L3 ring + relaxed agent-scope flags (3 hops/chain).
__global__ __launch_bounds__(TPB, 2) void k_lstm(
    const float* __restrict__ wih, const float* __restrict__ whh,
    const float* __restrict__ bih, const float* __restrict__ bhh,
    const float* __restrict__ seq0, float* __restrict__ ring,
    int* __restrict__ prog, int* __restrict__ cons,
    float* __restrict__ hfin)
{
  const int bid = blockIdx.x;          // 0..255
  const int c   = bid >> 2;            // chain = batch element
  const int seg = bid & 3;
  const int tid = threadIdx.x;
  const int ll  = tid / 12;            // 0..31 (30,31 idle)
  const int j   = tid - ll * 12;
  const bool act = (ll < SEG);
  const int l   = seg * SEG + ll;      // global layer

  // gate weights as (i,f) and (g,o) float2 pairs -> v_pk_fma_f32
  v2f wx_if[12], wx_go[12], whf_if[12], whf_go[12];
  v2f b_if = (v2f){0.f, 0.f}, b_go = (v2f){0.f, 0.f};
  if (act) {
    const float* wi = wih + l * 576;
    const float* wh = whh + l * 576;
#pragma unroll
    for (int k = 0; k < 12; ++k) {
      wx_if[k]  = (v2f){ wi[(j     ) * 12 + k], wi[(j + 12) * 12 + k] };
      wx_go[k]  = (v2f){ wi[(j + 24) * 12 + k], wi[(j + 36) * 12 + k] };
      whf_if[k] = (v2f){ wh[(j     ) * 12 + k], wh[(j + 12) * 12 + k] };
      whf_go[k] = (v2f){ wh[(j + 24) * 12 + k], wh[(j + 36) * 12 + k] };
    }
    const float* ba = bih + l * 48;
    const float* bb = bhh + l * 48;
    b_if = (v2f){ ba[j]      + bb[j],      ba[j + 12] + bb[j + 12] };
    b_go = (v2f){ ba[j + 24] + bb[j + 24], ba[j + 36] + bb[j + 36] };
  }

  __shared__ __align__(16) float hs[2][SEG * 12];
  if (tid < SEG * 12) { hs[0][tid] = 0.f; hs[1][tid] = 0.f; }
  __syncthreads();

  const int rin_idx  = c * 3 + seg - 1;          // valid if seg>0
  const int rout_idx = c * 3 + seg;              // valid if seg<3
  const float* rin  = (seg > 0) ? (ring + (size_t)rin_idx  * (RW * 12)) : nullptr;
  float*       rout = (seg < 3) ? (ring + (size_t)rout_idx * (RW * 12)) : nullptr;

  float cst = 0.f, hn = 0.f;
  int kp = 0, kc = 0;
  const bool feeder = act && (ll == 0);          // consumes x from seq0/ring
  const bool tailer = act && (ll == SEG - 1) && (seg < 3);  // produces into ring

  // ---- prologue: fetch x(0) for ll==0 ----
  float xv[12];
  if (feeder) {
    if (seg == 0) {
      const float4* p = (const float4*)(seq0 + (size_t)c * 12);
      float4 a = p[0], b4 = p[1], d = p[2];
      xv[0]=a.x; xv[1]=a.y; xv[2]=a.z; xv[3]=a.w;
      xv[4]=b4.x; xv[5]=b4.y; xv[6]=b4.z; xv[7]=b4.w;
      xv[8]=d.x; xv[9]=d.y; xv[10]=d.z; xv[11]=d.w;
    } else {
      kp = poll_ge_rlx(&prog[rin_idx], 1, kp);
      const float* base = rin;                   // slot 0
#pragma unroll
      for (int k = 0; k < 12; ++k)
        xv[k] = __hip_atomic_load(&base[k], __ATOMIC_RELAXED, __HIP_MEMORY_SCOPE_AGENT);
    }
  }

  for (int s = 0; s < TT + SEG - 1; ++s) {
    const int t = s - ll;
    const bool run = act && (t >= 0) && (t < TT);

    // ---- prefetch x(s+1) for ll==0 (consumed next step; latency off critical path) ----
    float pv[12];
    const bool pf = feeder && (s + 1 < TT);
    if (pf) {
      if (seg == 0) {
        const float4* p = (const float4*)(seq0 + (size_t)(s + 1) * 768 + c * 12);
        float4 a = p[0], b4 = p[1], d = p[2];
        pv[0]=a.x; pv[1]=a.y; pv[2]=a.z; pv[3]=a.w;
        pv[4]=b4.x; pv[5]=b4.y; pv[6]=b4.z; pv[7]=b4.w;
        pv[8]=d.x; pv[9]=d.y; pv[10]=d.z; pv[11]=d.w;
      } else {
        if (kp < s + 2) kp = poll_ge_rlx(&prog[rin_idx], s + 2, kp);
        const float* base = rin + ((s + 1) & (RW - 1)) * 12;
#pragma unroll
        for (int k = 0; k < 12; ++k)
          pv[k] = __hip_atomic_load(&base[k], __ATOMIC_RELAXED, __HIP_MEMORY_SCOPE_AGENT);
      }
    }
    // ---- producer backpressure: don't lap the 64-slot ring (window 47, margin 17) ----
    if (tailer) {
      int t2 = s - (SEG - 1);
      if (t2 >= 48 && kc < t2 - 47) kc = poll_ge_rlx(&cons[rout_idx], t2 - 47, kc);
    }

    if (run) {
      const int pb = (s & 1) ^ 1;   // buffer written at step s-1
      float xl[12];
      if (ll == 0) {
#pragma unroll
        for (int k = 0; k < 12; ++k) xl[k] = xv[k];
      } else {
        const float4* p = (const float4*)(&hs[pb][(ll - 1) * 12]);
        float4 a = p[0], b4 = p[1], d = p[2];
        xl[0]=a.x; xl[1]=a.y; xl[2]=a.z; xl[3]=a.w;
        xl[4]=b4.x; xl[5]=b4.y; xl[6]=b4.z; xl[7]=b4.w;
        xl[8]=d.x; xl[9]=d.y; xl[10]=d.z; xl[11]=d.w;
      }
      float hv[12];
      {
        const float4* p = (const float4*)(&hs[pb][ll * 12]);
        float4 a = p[0], b4 = p[1], d = p[2];
        hv[0]=a.x; hv[1]=a.y; hv[2]=a.z; hv[3]=a.w;
        hv[4]=b4.x; hv[5]=b4.y; hv[6]=b4.z; hv[7]=b4.w;
        hv[8]=d.x; hv[9]=d.y; hv[10]=d.z; hv[11]=d.w;
      }
      v2f aif = b_if, ago = b_go;
#pragma unroll
      for (int k = 0; k < 12; ++k) {
        v2f xx = { xl[k], xl[k] };
        aif = __builtin_elementwise_fma(wx_if[k], xx, aif);
        ago = __builtin_elementwise_fma(wx_go[k], xx, ago);
      }
#pragma unroll
      for (int k = 0; k < 12; ++k) {
        v2f hh = { hv[k], hv[k] };
        aif = __builtin_elementwise_fma(whf_if[k], hh, aif);
        ago = __builtin_elementwise_fma(whf_go[k], hh, ago);
      }
      float ig = fast_sig(aif.x);
      float fg = fast_sig(aif.y);
      float gg = fast_tanh(ago.x);
      float og = fast_sig(ago.y);
      cst = fg * cst + ig * gg;
      hn  = og * fast_tanh(cst);

      hs[s & 1][ll * 12 + j] = hn;
      if (tailer)   // publish h of layer seg*30+29 into the ring (L3, agent-coherent)
        __hip_atomic_store(&rout[(t & (RW - 1)) * 12 + j], hn,
                           __ATOMIC_RELAXED, __HIP_MEMORY_SCOPE_AGENT);
      if (t == TT - 1)
        hfin[l * 768 + c * 12 + j] = hn;
    }

    __syncthreads();   // drains each wave's stores (vmcnt0) before anyone proceeds

    if (tid == 0) {
      if (seg < 3) {
        int tp = s - (SEG - 1);
        if (tp >= 0 && tp < TT)
          __hip_atomic_store(&prog[rout_idx], tp + 1, __ATOMIC_RELAXED, __HIP_MEMORY_SCOPE_AGENT);
      }
      if (seg > 0 && s < TT && (((s & 15) == 15) || s == TT - 1))
        __hip_atomic_store(&cons[rin_idx], s + 1, __ATOMIC_RELAXED, __HIP_MEMORY_SCOPE_AGENT);
    }
    if (pf) {
#pragma unroll
      for (int k = 0; k < 12; ++k) xv[k] = pv[k];
    }
  }
}

// ---------------- head: lin1+relu, lin2+relu, mu, softplus(sigma) ----------------
__global__ void k_head(const float* __restrict__ hfin,
                       const float* __restrict__ w1, const float* __restrict__ b1,
                       const float* __restrict__ w2, const float* __restrict__ b2,
                       const float* __restrict__ wm, const float* __restrict__ bm,
                       const float* __restrict__ wsg, const float* __restrict__ bsg,
                       float* __restrict__ out)
{
  const int tid = threadIdx.x;
  __shared__ float s1[144], s2[144], sm[144], ss[144];
  __shared__ float v1[12], v2[12], vm[12], vs[12];
  if (tid < 144) { s1[tid] = w1[tid]; s2[tid] = w2[tid]; sm[tid] = wm[tid]; ss[tid] = wsg[tid]; }
  if (tid < 12)  { v1[tid] = b1[tid]; v2[tid] = b2[tid]; vm[tid] = bm[tid]; vs[tid] = bsg[tid]; }
  __syncthreads();
  const int r = blockIdx.x * 256 + tid;   // 0..7679 = b*120 + l
  const int b = r / 120, l = r - b * 120;
  float h[12];
#pragma unroll
  for (int k = 0; k < 12; ++k) h[k] = hfin[l * 768 + b * 12 + k];
  float u1[12];
#pragma unroll
  for (int u = 0; u < 12; ++u) {
    float a = v1[u];
#pragma unroll
    for (int k = 0; k < 12; ++k) a += s1[u * 12 + k] * h[k];
    u1[u] = fmaxf(a, 0.f);
  }
  float u2[12];
#pragma unroll
  for (int u = 0; u < 12; ++u) {
    float a = v2[u];
#pragma unroll
    for (int k = 0; k < 12; ++k) a += s2[u * 12 + k] * u1[k];
    u2[u] = fmaxf(a, 0.f);
  }
  const size_t base = (size_t)r * 12;
#pragma unroll
  for (int u = 0; u < 12; ++u) out[base + u] = u2[u];
#pragma unroll
  for (int u = 0; u < 12; ++u) {
    float a = vm[u];
#pragma unroll
    for (int k = 0; k < 12; ++k) a += sm[u * 12 + k] * u2[k];
    out[92160 + base + u] = a;
  }
#pragma unroll
  for (int u = 0; u < 12; ++u) {
    float a = vs[u];
#pragma unroll
    for (int k = 0; k < 12; ++k) a += ss[u * 12 + k] * u2[k];
    out[184320 + base + u] = fmaxf(a, 0.f) + log1pf(expf(-fabsf(a)));
  }
}

// ---------------- launcher ----------------
extern "C" void kernel_launch(void* const* d_in, const int* in_sizes, int n_in,
                              void* d_out, int out_size, void* d_ws, size_t ws_size,
                              hipStream_t stream)
{
  const float* x   = (const float*)d_in[0];
  const float* c1w = (const float*)d_in[1];
  const float* c1b = (const float*)d_in[2];
  const float* g1  = (const float*)d_in[3];
  const float* be1 = (const float*)d_in[4];
  const float* c2w = (const float*)d_in[5];
  const float* c2b = (const float*)d_in[6];
  const float* g2  = (const float*)d_in[7];
  const float* be2 = (const float*)d_in[8];
  const float* aw  = (const float*)d_in[9];
  const float* ab  = (const float*)d_in[10];
  const float* wih = (const float*)d_in[11];
  const float* whh = (const float*)d_in[12];
  const float* bih = (const float*)d_in[13];
  const float* bhh = (const float*)d_in[14];
  const float* l1w = (const float*)d_in[15];
  const float* l1b = (const float*)d_in[16];
  const float* l2w = (const float*)d_in[17];
  const float* l2b = (const float*)d_in[18];
  const float* muw = (const float*)d_in[19];
  const float* mub = (const float*)d_in[20];
  const float* sgw = (const float*)d_in[21];
  const float* sgb = (const float*)d_in[22];

  float* ws    = (float*)d_ws;
  float* stat1 = ws;                    // 12
  float* stat2 = ws + 12;               // 12
  float* aff1  = ws + 24;               // 12 (scale[6], shift[6])
  float* aff2  = ws + 36;               // 12
  int*   prog  = (int*)(ws + 64);       // 192 used
  int*   cons  = (int*)(ws + 304);      // 192 used
  float* y1    = ws + 576;              // 64*6*1020
  float* y2    = y1 + 391680;           // 64*6*1016
  float* seq0  = y2 + 390144;           // 1016*768
  float* ring  = seq0 + 780288;         // 192 hops * 64 slots * 12
  float* hfin  = ring + 147456;         // 120*768

  hipMemsetAsync(d_ws, 0, 576 * sizeof(float), stream);  // zero stats + flags

  k_conv<<<384, 256, 0, stream>>>(x, c1w, c1b, nullptr, y1, stat1, 1024, 1020, 0);
  k_finalize<<<1, 64, 0, stream>>>(stat1, g1, be1, aff1, 1.f / 65280.f);
  k_conv<<<384, 256, 0, stream>>>(y1, c2w, c2b, aff1, y2, stat2, 1020, 1016, 1);
  k_finalize<<<1, 64, 0, stream>>>(stat2, g2, be2, aff2, 1.f / 65024.f);
  k_attn<<<1016, 768, 0, stream>>>(y2, aff2, aw, ab, seq0);
  k_lstm<<<256, TPB, 0, stream>>>(wih, whh, bih, bhh, seq0, ring, prog, cons, hfin);
  k_head<<<30, 256, 0, stream>>>(hfin, l1w, l1b, l2w, l2b, muw, mub, sgw, sgb, (float*)d_out);
}

// Round 3
// 1093.603 us; speedup vs baseline: 4.4730x; 1.3854x over previous
//
#include <hip/hip_runtime.h>
#include <math.h>

// ---------------- problem constants ----------------
#define NLAY 120         // LSTM layers
#define TT   1016        // LSTM time steps (1024 - 4 - 4)
#define SEG  30          // layers per block
#define G    16          // hand-off batch (time steps)
#define NB   64          // ceil(TT/G)
#define RB   8           // ring depth in batches (power of 2)
#define TPB  384         // threads per LSTM block: 30 layers x 12 hidden = 360 active

typedef float v2f __attribute__((ext_vector_type(2)));

__device__ __forceinline__ float fast_rcp(float x) { return __builtin_amdgcn_rcpf(x); }
__device__ __forceinline__ float fast_sig(float x) { return fast_rcp(1.f + __expf(-x)); }
__device__ __forceinline__ float fast_tanh(float x) { return 1.f - 2.f * fast_rcp(1.f + __expf(2.f * x)); }

// relaxed agent-scope poll (L2-bypassing load); watchdog fails loud, never hangs
__device__ __forceinline__ int poll_ge_rlx(const int* p, int target, int cur) {
  long g = 0;
  while (cur < target) {
    cur = __hip_atomic_load(p, __ATOMIC_RELAXED, __HIP_MEMORY_SCOPE_AGENT);
    if (++g > 5000000L) break;
  }
  return cur;
}

// ---------------- conv1d(6->6,K=5,valid) + bias, accumulate BN stats ----------------
__global__ void k_conv(const float* __restrict__ xin, const float* __restrict__ cw,
                       const float* __restrict__ cb, const float* __restrict__ aff,
                       float* __restrict__ yout, float* __restrict__ stat,
                       int Tin, int Tout, int use_aff)
{
  const int bx = blockIdx.x;            // 0..383 : b*6+co
  const int b = bx / 6, co = bx - b * 6;
  const int tid = threadIdx.x;          // 256
  __shared__ float wsh[30];
  __shared__ float ssh[6], shsh[6];
  if (tid < 30) wsh[tid] = cw[co * 30 + tid];
  if (tid < 6) {
    ssh[tid]  = use_aff ? aff[tid] : 1.f;
    shsh[tid] = use_aff ? aff[6 + tid] : 0.f;
  }
  __syncthreads();
  const float bias = cb[co];
  float lsum = 0.f, lsq = 0.f;
  for (int t = tid; t < Tout; t += 256) {
    float acc = bias;
#pragma unroll
    for (int ci = 0; ci < 6; ++ci) {
      const float* xr = xin + ((size_t)b * 6 + ci) * Tin + t;
      const float s = ssh[ci], sh = shsh[ci];
#pragma unroll
      for (int k = 0; k < 5; ++k) {
        float v = xr[k];
        if (use_aff) v = fmaxf(fmaf(s, v, sh), 0.f);
        acc += wsh[ci * 5 + k] * v;
      }
    }
    yout[((size_t)b * 6 + co) * Tout + t] = acc;
    lsum += acc; lsq += acc * acc;
  }
  __shared__ float rs[256], rq[256];
  rs[tid] = lsum; rq[tid] = lsq;
  __syncthreads();
  for (int s = 128; s > 0; s >>= 1) {
    if (tid < s) { rs[tid] += rs[tid + s]; rq[tid] += rq[tid + s]; }
    __syncthreads();
  }
  if (tid == 0) { atomicAdd(&stat[co], rs[0]); atomicAdd(&stat[6 + co], rq[0]); }
}

// ---------------- finalize BN: stats -> per-channel scale/shift ----------------
__global__ void k_finalize(const float* __restrict__ stat,
                           const float* __restrict__ gamma, const float* __restrict__ beta,
                           float* __restrict__ aff, float invN)
{
  const int c = threadIdx.x;
  if (c < 6) {
    float mean = stat[c] * invN;
    float var  = stat[6 + c] * invN - mean * mean;
    float sc   = gamma[c] * rsqrtf(var + 1e-5f);
    aff[c]     = sc;
    aff[6 + c] = fmaf(-mean, sc, beta[c]);
  }
}

// ---------------- BN2+ReLU + attn projection (6->12) + ReLU; write seq0[t][b*12+j] ----------------
__global__ void k_attn(const float* __restrict__ y2, const float* __restrict__ aff2,
                       const float* __restrict__ aw, const float* __restrict__ ab,
                       float* __restrict__ seq0)
{
  const int t = blockIdx.x;             // 0..1015
  const int tid = threadIdx.x;          // 0..767
  __shared__ float zb[6 * 64];
  if (tid < 384) {
    const int c = tid >> 6, bb = tid & 63;
    float v = y2[((size_t)bb * 6 + c) * TT + t];
    zb[c * 64 + bb] = fmaxf(fmaf(aff2[c], v, aff2[6 + c]), 0.f);
  }
  __syncthreads();
  const int b = tid / 12, j = tid - b * 12;
  float acc = ab[j];
#pragma unroll
  for (int c = 0; c < 6; ++c) acc += aw[j * 6 + c] * zb[c * 64 + b];
  seq0[(size_t)t * 768 + tid] = fmaxf(acc, 0.f);
}

// ---------------- 120-layer LSTM: 30 layers/block, LDS wavefront, BATCHED ring hand-off ----------------
// grid = 256 blocks: bid = chain*4 + seg. Diagonal schedule: layer ll computes t = s - ll.
// Intra-block hand-off: double-buffered LDS, 1 barrier/step (no global ops on 15/16 steps).
// Inter-segment: 16-step batches through L3 ring (8 batches deep), relaxed agent atomics;
// tailer stages h in LDS obuf and flushes per batch; feeder copies batch -> LDS xbuf ahead.
__global__ __launch_bounds__(TPB, 2) void k_lstm(
    const float* __restrict__ wih, const float* __restrict__ whh,
    const float* __restrict__ bih, const float* __restrict__ bhh,
    const float* __restrict__ seq0, float* __restrict__ ring,
    int* __restrict__ prog, int* __restrict__ cons,
    float* __restrict__ hfin)
{
  const int bid = blockIdx.x;          // 0..255
  const int c   = bid >> 2;            // chain = batch element
  const int seg = bid & 3;
  const int tid = threadIdx.x;
  const int ll  = tid / 12;            // 0..31 (30,31 idle)
  const int j   = tid - ll * 12;
  const bool act = (ll < SEG);
  const int l   = seg * SEG + ll;      // global layer

  v2f wx_if[12], wx_go[12], whf_if[12], whf_go[12];
  v2f b_if = (v2f){0.f, 0.f}, b_go = (v2f){0.f, 0.f};
  if (act) {
    const float* wi = wih + l * 576;
    const float* wh = whh + l * 576;
#pragma unroll
    for (int k = 0; k < 12; ++k) {
      wx_if[k]  = (v2f){ wi[(j     ) * 12 + k], wi[(j + 12) * 12 + k] };
      wx_go[k]  = (v2f){ wi[(j + 24) * 12 + k], wi[(j + 36) * 12 + k] };
      whf_if[k] = (v2f){ wh[(j     ) * 12 + k], wh[(j + 12) * 12 + k] };
      whf_go[k] = (v2f){ wh[(j + 24) * 12 + k], wh[(j + 36) * 12 + k] };
    }
    const float* ba = bih + l * 48;
    const float* bb = bhh + l * 48;
    b_if = (v2f){ ba[j]      + bb[j],      ba[j + 12] + bb[j + 12] };
    b_go = (v2f){ ba[j + 24] + bb[j + 24], ba[j + 36] + bb[j + 36] };
  }

  __shared__ __align__(16) float hs[2][SEG * 12];
  __shared__ __align__(16) float xbuf[2][G * 12];   // incoming x batches (layer 0 reads)
  __shared__ __align__(16) float obuf[G * 12];      // outgoing h staging (layer SEG-1)
  if (tid < SEG * 12) { hs[0][tid] = 0.f; hs[1][tid] = 0.f; }

  const int rin_idx  = c * 3 + seg - 1;
  const int rout_idx = c * 3 + seg;
  const float* rin  = (seg > 0) ? (ring + (size_t)rin_idx  * (RB * G * 12)) : nullptr;
  float*       rout = (seg < 3) ? (ring + (size_t)rout_idx * (RB * G * 12)) : nullptr;

  const bool feeder = act && (ll == 0);
  const bool tailer = act && (ll == SEG - 1) && (seg < 3);
  int kp = 0, kc = 0;

  // ---- prologue: copy batch 0 into xbuf[0] ----
  if (feeder) {
    if (seg == 0) {
      const float* src = seq0 + (size_t)c * 12 + j;
#pragma unroll
      for (int i = 0; i < G; ++i) xbuf[0][i * 12 + j] = src[(size_t)i * 768];
    } else {
      kp = poll_ge_rlx(&prog[rin_idx], 1, kp);
      const float* src = rin + j * 16;             // batch 0 region
      float v[16];
#pragma unroll
      for (int q = 0; q < 16; ++q)
        v[q] = __hip_atomic_load(src + q, __ATOMIC_RELAXED, __HIP_MEMORY_SCOPE_AGENT);
      float4* dst = (float4*)&xbuf[0][j * 16];
      dst[0] = (float4){v[0], v[1], v[2], v[3]};
      dst[1] = (float4){v[4], v[5], v[6], v[7]};
      dst[2] = (float4){v[8], v[9], v[10], v[11]};
      dst[3] = (float4){v[12], v[13], v[14], v[15]};
    }
  }
  __syncthreads();
  if (tid == 0 && seg > 0)
    __hip_atomic_store(&cons[rin_idx], 1, __ATOMIC_RELAXED, __HIP_MEMORY_SCOPE_AGENT);

  float cst = 0.f, hn = 0.f;

  for (int s = 0; s < TT + SEG; ++s) {
    const int t = s - ll;
    const bool run = act && (t >= 0) && (t < TT);

    // ---- feeder: at phase 0 of batch m, prefetch batch m+1 into xbuf[(m+1)&1] ----
    if (feeder && t >= 0 && t < TT && (t & 15) == 0) {
      const int m = t >> 4;
      if (m + 1 < NB) {
        if (seg == 0) {
          const int base_t = (m + 1) * G;
          const float* src = seq0 + (size_t)base_t * 768 + c * 12 + j;
#pragma unroll
          for (int i = 0; i < G; ++i) {
            float v = (base_t + i < TT) ? src[(size_t)i * 768] : 0.f;
            xbuf[(m + 1) & 1][i * 12 + j] = v;
          }
        } else {
          if (kp < m + 2) kp = poll_ge_rlx(&prog[rin_idx], m + 2, kp);
          const float* src = rin + ((m + 1) & (RB - 1)) * (G * 12) + j * 16;
          float v[16];
#pragma unroll
          for (int q = 0; q < 16; ++q)
            v[q] = __hip_atomic_load(src + q, __ATOMIC_RELAXED, __HIP_MEMORY_SCOPE_AGENT);
          float4* dst = (float4*)&xbuf[(m + 1) & 1][j * 16];
          dst[0] = (float4){v[0], v[1], v[2], v[3]};
          dst[1] = (float4){v[4], v[5], v[6], v[7]};
          dst[2] = (float4){v[8], v[9], v[10], v[11]};
          dst[3] = (float4){v[12], v[13], v[14], v[15]};
        }
      }
    }

    // ---- tailer: flush previous batch (read obuf transposed BEFORE this step's write) ----
    if (tailer && t > 0 && (((t & 15) == 0) || t == TT)) {
      const int m2 = (t - 1) >> 4;
      if (m2 >= RB) kc = poll_ge_rlx(&cons[rout_idx], m2 - (RB - 1), kc);
      const float4* ob = (const float4*)&obuf[j * 16];
      float4 o0 = ob[0], o1 = ob[1], o2 = ob[2], o3 = ob[3];
      float ov[16] = {o0.x,o0.y,o0.z,o0.w, o1.x,o1.y,o1.z,o1.w,
                      o2.x,o2.y,o2.z,o2.w, o3.x,o3.y,o3.z,o3.w};
      float* dst = rout + (m2 & (RB - 1)) * (G * 12) + j * 16;
#pragma unroll
      for (int q = 0; q < 16; ++q)
        __hip_atomic_store(dst + q, ov[q], __ATOMIC_RELAXED, __HIP_MEMORY_SCOPE_AGENT);
    }

    if (run) {
      const int pb = (s & 1) ^ 1;
      float xl[12];
      if (ll == 0) {
        const float4* p = (const float4*)&xbuf[(t >> 4) & 1][(t & 15) * 12];
        float4 a = p[0], b4 = p[1], d = p[2];
        xl[0]=a.x; xl[1]=a.y; xl[2]=a.z; xl[3]=a.w;
        xl[4]=b4.x; xl[5]=b4.y; xl[6]=b4.z; xl[7]=b4.w;
        xl[8]=d.x; xl[9]=d.y; xl[10]=d.z; xl[11]=d.w;
      } else {
        const float4* p = (const float4*)&hs[pb][(ll - 1) * 12];
        float4 a = p[0], b4 = p[1], d = p[2];
        xl[0]=a.x; xl[1]=a.y; xl[2]=a.z; xl[3]=a.w;
        xl[4]=b4.x; xl[5]=b4.y; xl[6]=b4.z; xl[7]=b4.w;
        xl[8]=d.x; xl[9]=d.y; xl[10]=d.z; xl[11]=d.w;
      }
      float hv[12];
      {
        const float4* p = (const float4*)&hs[pb][ll * 12];
        float4 a = p[0], b4 = p[1], d = p[2];
        hv[0]=a.x; hv[1]=a.y; hv[2]=a.z; hv[3]=a.w;
        hv[4]=b4.x; hv[5]=b4.y; hv[6]=b4.z; hv[7]=b4.w;
        hv[8]=d.x; hv[9]=d.y; hv[10]=d.z; hv[11]=d.w;
      }
      v2f aif = b_if, ago = b_go;
#pragma unroll
      for (int k = 0; k < 12; ++k) {
        v2f xx = { xl[k], xl[k] };
        aif = __builtin_elementwise_fma(wx_if[k], xx, aif);
        ago = __builtin_elementwise_fma(wx_go[k], xx, ago);
      }
#pragma unroll
      for (int k = 0; k < 12; ++k) {
        v2f hh = { hv[k], hv[k] };
        aif = __builtin_elementwise_fma(whf_if[k], hh, aif);
        ago = __builtin_elementwise_fma(whf_go[k], hh, ago);
      }
      float ig = fast_sig(aif.x);
      float fg = fast_sig(aif.y);
      float gg = fast_tanh(ago.x);
      float og = fast_sig(ago.y);
      cst = fg * cst + ig * gg;
      hn  = og * fast_tanh(cst);

      hs[s & 1][ll * 12 + j] = hn;
      if (tailer) obuf[(t & 15) * 12 + j] = hn;   // intra-wave staging, no barrier needed
      if (t == TT - 1) hfin[l * 768 + c * 12 + j] = hn;
    }

    __syncthreads();

    if (tid == 0) {
      if (seg < 3) {
        const int tp = s - (SEG - 1);
        if (tp > 0 && (((tp & 15) == 0) || tp == TT))
          __hip_atomic_store(&prog[rout_idx], ((tp - 1) >> 4) + 1,
                             __ATOMIC_RELAXED, __HIP_MEMORY_SCOPE_AGENT);
      }
      if (seg > 0 && s < TT && (s & 15) == 0) {
        const int m = s >> 4;
        if (m + 1 < NB)
          __hip_atomic_store(&cons[rin_idx], m + 2,
                             __ATOMIC_RELAXED, __HIP_MEMORY_SCOPE_AGENT);
      }
    }
  }
}

// ---------------- head: lin1+relu, lin2+relu, mu, softplus(sigma) ----------------
__global__ void k_head(const float* __restrict__ hfin,
                       const float* __restrict__ w1, const float* __restrict__ b1,
                       const float* __restrict__ w2, const float* __restrict__ b2,
                       const float* __restrict__ wm, const float* __restrict__ bm,
                       const float* __restrict__ wsg, const float* __restrict__ bsg,
                       float* __restrict__ out)
{
  const int tid = threadIdx.x;
  __shared__ float s1[144], s2[144], sm[144], ss[144];
  __shared__ float v1[12], v2[12], vm[12], vs[12];
  if (tid < 144) { s1[tid] = w1[tid]; s2[tid] = w2[tid]; sm[tid] = wm[tid]; ss[tid] = wsg[tid]; }
  if (tid < 12)  { v1[tid] = b1[tid]; v2[tid] = b2[tid]; vm[tid] = bm[tid]; vs[tid] = bsg[tid]; }
  __syncthreads();
  const int r = blockIdx.x * 256 + tid;   // 0..7679 = b*120 + l
  const int b = r / 120, l = r - b * 120;
  float h[12];
#pragma unroll
  for (int k = 0; k < 12; ++k) h[k] = hfin[l * 768 + b * 12 + k];
  float u1[12];
#pragma unroll
  for (int u = 0; u < 12; ++u) {
    float a = v1[u];
#pragma unroll
    for (int k = 0; k < 12; ++k) a += s1[u * 12 + k] * h[k];
    u1[u] = fmaxf(a, 0.f);
  }
  float u2[12];
#pragma unroll
  for (int u = 0; u < 12; ++u) {
    float a = v2[u];
#pragma unroll
    for (int k = 0; k < 12; ++k) a += s2[u * 12 + k] * u1[k];
    u2[u] = fmaxf(a, 0.f);
  }
  const size_t base = (size_t)r * 12;
#pragma unroll
  for (int u = 0; u < 12; ++u) out[base + u] = u2[u];
#pragma unroll
  for (int u = 0; u < 12; ++u) {
    float a = vm[u];
#pragma unroll
    for (int k = 0; k < 12; ++k) a += sm[u * 12 + k] * u2[k];
    out[92160 + base + u] = a;
  }
#pragma unroll
  for (int u = 0; u < 12; ++u) {
    float a = vs[u];
#pragma unroll
    for (int k = 0; k < 12; ++k) a += ss[u * 12 + k] * u2[k];
    out[184320 + base + u] = fmaxf(a, 0.f) + log1pf(expf(-fabsf(a)));
  }
}

// ---------------- launcher ----------------
extern "C" void kernel_launch(void* const* d_in, const int* in_sizes, int n_in,
                              void* d_out, int out_size, void* d_ws, size_t ws_size,
                              hipStream_t stream)
{
  const float* x   = (const float*)d_in[0];
  const float* c1w = (const float*)d_in[1];
  const float* c1b = (const float*)d_in[2];
  const float* g1  = (const float*)d_in[3];
  const float* be1 = (const float*)d_in[4];
  const float* c2w = (const float*)d_in[5];
  const float* c2b = (const float*)d_in[6];
  const float* g2  = (const float*)d_in[7];
  const float* be2 = (const float*)d_in[8];
  const float* aw  = (const float*)d_in[9];
  const float* ab  = (const float*)d_in[10];
  const float* wih = (const float*)d_in[11];
  const float* whh = (const float*)d_in[12];
  const float* bih = (const float*)d_in[13];
  const float* bhh = (const float*)d_in[14];
  const float* l1w = (const float*)d_in[15];
  const float* l1b = (const float*)d_in[16];
  const float* l2w = (const float*)d_in[17];
  const float* l2b = (const float*)d_in[18];
  const float* muw = (const float*)d_in[19];
  const float* mub = (const float*)d_in[20];
  const float* sgw = (const float*)d_in[21];
  const float* sgb = (const float*)d_in[22];

  float* ws    = (float*)d_ws;
  float* stat1 = ws;                    // 12
  float* stat2 = ws + 12;               // 12
  float* aff1  = ws + 24;               // 12
  float* aff2  = ws + 36;               // 12
  int*   prog  = (int*)(ws + 64);       // 192 used
  int*   cons  = (int*)(ws + 304);      // 192 used
  float* y1    = ws + 576;              // 64*6*1020
  float* y2    = y1 + 391680;           // 64*6*1016
  float* seq0  = y2 + 390144;           // 1016*768
  float* ring  = seq0 + 780288;         // 192 hops * 8 batches * 192 floats
  float* hfin  = ring + (size_t)192 * RB * G * 12;  // 120*768

  hipMemsetAsync(d_ws, 0, 576 * sizeof(float), stream);  // zero stats + flags

  k_conv<<<384, 256, 0, stream>>>(x, c1w, c1b, nullptr, y1, stat1, 1024, 1020, 0);
  k_finalize<<<1, 64, 0, stream>>>(stat1, g1, be1, aff1, 1.f / 65280.f);
  k_conv<<<384, 256, 0, stream>>>(y1, c2w, c2b, aff1, y2, stat2, 1020, 1016, 1);
  k_finalize<<<1, 64, 0, stream>>>(stat2, g2, be2, aff2, 1.f / 65024.f);
  k_attn<<<1016, 768, 0, stream>>>(y2, aff2, aw, ab, seq0);
  k_lstm<<<256, TPB, 0, stream>>>(wih, whh, bih, bhh, seq0, ring, prog, cons, hfin);
  k_head<<<30, 256, 0, stream>>>(hfin, l1w, l1b, l2w, l2b, muw, mub, sgw, sgb, (float*)d_out);
}

// Round 4
// 856.588 us; speedup vs baseline: 5.7106x; 1.2767x over previous
//
#include <hip/hip_runtime.h>
#include <math.h>

// ---------------- problem constants ----------------
#define NLAY 120         // LSTM layers
#define TT   1016        // LSTM time steps (1024 - 4 - 4)
#define NB   64          // batches of 16 steps (64*16 = 1024 >= TT+4)
#define RB   8           // L3 ring depth in batches (power of 2)
#define IRS  32          // intra-block inter-wave LDS ring slots (power of 2)
#define TPB  384         // 6 waves x 64 lanes; wave = 5 layers x 12 hidden (lanes 60-63 idle)
#define BIGF (1 << 20)

typedef float v2f __attribute__((ext_vector_type(2)));

__device__ __forceinline__ float fast_rcp(float x) { return __builtin_amdgcn_rcpf(x); }
__device__ __forceinline__ float fast_sig(float x) { return fast_rcp(1.f + __expf(-x)); }
__device__ __forceinline__ float fast_tanh(float x) { return 1.f - 2.f * fast_rcp(1.f + __expf(2.f * x)); }

// agent-scope relaxed poll (global flags; watchdog fails loud, never hangs)
__device__ __forceinline__ int poll_ge_ag(const int* p, int tgt, int cur) {
  long g = 0;
  while (cur < tgt) {
    cur = __hip_atomic_load(p, __ATOMIC_RELAXED, __HIP_MEMORY_SCOPE_AGENT);
    if (++g > 2000000L) break;
  }
  return cur;
}
// workgroup-scope relaxed poll on an LDS flag (ds_read spin — no global traffic)
__device__ __forceinline__ int poll_ge_wg(const int* p, int tgt, int cur) {
  long g = 0;
  while (cur < tgt) {
    cur = __hip_atomic_load(p, __ATOMIC_RELAXED, __HIP_MEMORY_SCOPE_WORKGROUP);
    if (++g > 2000000L) break;
  }
  return cur;
}

// ---------------- conv1d(6->6,K=5,valid) + bias, accumulate BN stats ----------------
__global__ void k_conv(const float* __restrict__ xin, const float* __restrict__ cw,
                       const float* __restrict__ cb, const float* __restrict__ aff,
                       float* __restrict__ yout, float* __restrict__ stat,
                       int Tin, int Tout, int use_aff)
{
  const int bx = blockIdx.x;            // 0..383 : b*6+co
  const int b = bx / 6, co = bx - b * 6;
  const int tid = threadIdx.x;          // 256
  __shared__ float wsh[30];
  __shared__ float ssh[6], shsh[6];
  if (tid < 30) wsh[tid] = cw[co * 30 + tid];
  if (tid < 6) {
    ssh[tid]  = use_aff ? aff[tid] : 1.f;
    shsh[tid] = use_aff ? aff[6 + tid] : 0.f;
  }
  __syncthreads();
  const float bias = cb[co];
  float lsum = 0.f, lsq = 0.f;
  for (int t = tid; t < Tout; t += 256) {
    float acc = bias;
#pragma unroll
    for (int ci = 0; ci < 6; ++ci) {
      const float* xr = xin + ((size_t)b * 6 + ci) * Tin + t;
      const float s = ssh[ci], sh = shsh[ci];
#pragma unroll
      for (int k = 0; k < 5; ++k) {
        float v = xr[k];
        if (use_aff) v = fmaxf(fmaf(s, v, sh), 0.f);
        acc += wsh[ci * 5 + k] * v;
      }
    }
    yout[((size_t)b * 6 + co) * Tout + t] = acc;
    lsum += acc; lsq += acc * acc;
  }
  __shared__ float rs[256], rq[256];
  rs[tid] = lsum; rq[tid] = lsq;
  __syncthreads();
  for (int s = 128; s > 0; s >>= 1) {
    if (tid < s) { rs[tid] += rs[tid + s]; rq[tid] += rq[tid + s]; }
    __syncthreads();
  }
  if (tid == 0) { atomicAdd(&stat[co], rs[0]); atomicAdd(&stat[6 + co], rq[0]); }
}

// ---------------- finalize BN: stats -> per-channel scale/shift ----------------
__global__ void k_finalize(const float* __restrict__ stat,
                           const float* __restrict__ gamma, const float* __restrict__ beta,
                           float* __restrict__ aff, float invN)
{
  const int c = threadIdx.x;
  if (c < 6) {
    float mean = stat[c] * invN;
    float var  = stat[6 + c] * invN - mean * mean;
    float sc   = gamma[c] * rsqrtf(var + 1e-5f);
    aff[c]     = sc;
    aff[6 + c] = fmaf(-mean, sc, beta[c]);
  }
}

// ---------------- BN2+ReLU + attn projection (6->12) + ReLU; write seq0[t][b*12+j] ----------------
__global__ void k_attn(const float* __restrict__ y2, const float* __restrict__ aff2,
                       const float* __restrict__ aw, const float* __restrict__ ab,
                       float* __restrict__ seq0)
{
  const int t = blockIdx.x;             // 0..1015
  const int tid = threadIdx.x;          // 0..767
  __shared__ float zb[6 * 64];
  if (tid < 384) {
    const int c = tid >> 6, bb = tid & 63;
    float v = y2[((size_t)bb * 6 + c) * TT + t];
    zb[c * 64 + bb] = fmaxf(fmaf(aff2[c], v, aff2[6 + c]), 0.f);
  }
  __syncthreads();
  const int b = tid / 12, j = tid - b * 12;
  float acc = ab[j];
#pragma unroll
  for (int c = 0; c < 6; ++c) acc += aw[j * 6 + c] * zb[c * 64 + b];
  seq0[(size_t)t * 768 + tid] = fmaxf(acc, 0.f);
}

// ---------------- 120-layer LSTM: free-running waves, NO in-loop barrier ----------------
// grid = 256 blocks: bid = chain*4 + seg; chain = batch element, seg = 30 layers.
// Wave w (of 6) = 5-layer pipeline stage; lane (p,j) = layer w*5+p, unit j (p<5).
// Diagonal: at wave-local step s, group p computes t = s - p.
// Intra-wave hand-off: per-wave double-buffered LDS (DS pipe is in-order per wave -> no sync).
// Wave->wave: 32-slot LDS ring + release/acquire LDS flags every 4 steps (no s_barrier).
// Block->block: 16-step batches via L3 ring (agent atomics), loads issued 16 steps ahead.
__global__ __launch_bounds__(TPB, 2) void k_lstm(
    const float* __restrict__ wih, const float* __restrict__ whh,
    const float* __restrict__ bih, const float* __restrict__ bhh,
    const float* __restrict__ seq0, float* __restrict__ ring,
    int* __restrict__ prog, int* __restrict__ cons,
    float* __restrict__ hfin)
{
  const int bid  = blockIdx.x;         // 0..255
  const int c    = bid >> 2;           // chain = batch element
  const int seg  = bid & 3;
  const int tid  = threadIdx.x;
  const int w    = tid >> 6;           // wave 0..5
  const int lane = tid & 63;
  const int p    = lane / 12;          // 0..5 (5 = idle in compute)
  const int j    = lane - p * 12;
  const bool act = (p < 5);
  const int pc   = act ? p : 0;        // clamped for safe addressing
  const int l    = seg * 30 + w * 5 + pc;

  // ---- LDS ----
  __shared__ __align__(16) float hloc[6][2][60];        // per-wave double buffer
  __shared__ __align__(16) float iring[5][IRS][12];     // wave w -> w+1
  __shared__ __align__(16) float xring[2][16][12];      // feeder input (wave 0 private)
  __shared__ __align__(16) float oring[16][12];         // tailer staging (wave 5 private)
  __shared__ int pflag[6];                              // produced-count, posted by wave w (w<5)
  __shared__ int cflag[8];                              // consumed-count, posted by wave w (w>0)
  float* xrf = &xring[0][0][0];

  if (tid < 6) pflag[tid] = 0;
  if (tid < 8) cflag[tid] = 0;
  if (lane < 60) { hloc[w][0][lane] = 0.f; hloc[w][1][lane] = 0.f; }
  __syncthreads();   // ONE barrier, before the main loop only

  // ---- gate weights as (i,f),(g,o) float2 pairs -> v_pk_fma_f32; split x/h chains ----
  v2f wx_if[12], wx_go[12], wh_if[12], wh_go[12];
  v2f b_if = (v2f){0.f, 0.f}, b_go = (v2f){0.f, 0.f};
  if (act) {
    const float* wi = wih + l * 576;
    const float* wh = whh + l * 576;
#pragma unroll
    for (int k = 0; k < 12; ++k) {
      wx_if[k] = (v2f){ wi[(j     ) * 12 + k], wi[(j + 12) * 12 + k] };
      wx_go[k] = (v2f){ wi[(j + 24) * 12 + k], wi[(j + 36) * 12 + k] };
      wh_if[k] = (v2f){ wh[(j     ) * 12 + k], wh[(j + 12) * 12 + k] };
      wh_go[k] = (v2f){ wh[(j + 24) * 12 + k], wh[(j + 36) * 12 + k] };
    }
    const float* ba = bih + l * 48;
    const float* bb = bhh + l * 48;
    b_if = (v2f){ ba[j]      + bb[j],      ba[j + 12] + bb[j + 12] };
    b_go = (v2f){ ba[j + 24] + bb[j + 24], ba[j + 36] + bb[j + 36] };
  }

  // ---- feeder / tailer plumbing ----
  const int hop_in  = c * 3 + seg - 1;                 // valid if seg>0
  const int hop_out = c * 3 + seg;                     // valid if seg<3
  const float* rin  = ring + (size_t)((seg > 0) ? hop_in : 0) * (RB * 192);
  float*       rout = ring + (size_t)((seg < 3) ? hop_out : 0) * (RB * 192);
  const bool is_feeder = (w == 0);
  const bool is_tailer = (w == 5) && (seg < 3);

  const int f0 = lane, f1 = lane + 64, f2 = lane + 128;   // cooperative 192-float copy
  const int s0o0 = (f0 / 12) * 768 + (f0 % 12);           // seq0 gather offsets
  const int s0o1 = (f1 / 12) * 768 + (f1 % 12);
  const int s0o2 = (f2 / 12) * 768 + (f2 % 12);

  auto ld_batch = [&](int m, float* d) {
    if (seg == 0) {
      const float* b = seq0 + (size_t)m * 16 * 768 + c * 12;
      d[0] = b[s0o0]; d[1] = b[s0o1]; d[2] = b[s0o2];
    } else {
      const float* b = rin + (m & (RB - 1)) * 192;
      d[0] = __hip_atomic_load(b + f0, __ATOMIC_RELAXED, __HIP_MEMORY_SCOPE_AGENT);
      d[1] = __hip_atomic_load(b + f1, __ATOMIC_RELAXED, __HIP_MEMORY_SCOPE_AGENT);
      d[2] = __hip_atomic_load(b + f2, __ATOMIC_RELAXED, __HIP_MEMORY_SCOPE_AGENT);
    }
  };

  float pend[3] = {0.f, 0.f, 0.f};
  int kp = 0, kcons = 0;
  if (is_feeder) {
    if (seg > 0) kp = poll_ge_ag(&prog[hop_in], 2, 0);
    float cur[3];
    ld_batch(0, cur);
    ld_batch(1, pend);
    xrf[f0] = cur[0]; xrf[f1] = cur[1]; xrf[f2] = cur[2];   // batch 0 -> buffer 0
  }

  float cst = 0.f;
  int pcache = 0, ccache = 0;

  for (int m = 0; m < NB; ++m) {
    // ---- feeder boundary: publish batch m+1, start loads for m+2 ----
    if (is_feeder) {
      if (m + 1 < NB) {
        float* xd = xrf + ((m + 1) & 1) * 192;
        xd[f0] = pend[0]; xd[f1] = pend[1]; xd[f2] = pend[2];
      }
      if (m + 2 < NB) {
        if (seg > 0 && kp < m + 3) kp = poll_ge_ag(&prog[hop_in], m + 3, kp);
        ld_batch(m + 2, pend);     // in flight for the next 16 steps
      }
      if (seg > 0 && lane == 0)
        __hip_atomic_store(&cons[hop_in], m, __ATOMIC_RELAXED, __HIP_MEMORY_SCOPE_AGENT);
    }

#pragma unroll
    for (int u = 0; u < 16; ++u) {
      const int s = m * 16 + u;

      // ---- flag sync every 4 steps (LDS only) ----
      if ((u & 3) == 0) {
        if (w > 0 && s < TT) {               // input availability for t = s..s+3
          int tgt = (s + 4 < TT) ? (s + 4) : TT;
          if (pcache < tgt) {
            pcache = poll_ge_wg(&pflag[w - 1], tgt, pcache);
            __builtin_amdgcn_fence(__ATOMIC_ACQUIRE, "workgroup");
          }
        }
        if (w < 5 && s >= 33) {              // don't lap the 32-slot iring
          int tgt = s - 32;
          if (ccache < tgt) ccache = poll_ge_wg(&cflag[w + 1], tgt, ccache);
        }
      }

      const int t  = s - pc;
      const bool run = act && (t >= 0) && (t < TT);
      const int rb = (s & 1) ^ 1, wb = s & 1;

      // ---- per-lane input addresses (single divergent select) ----
      const float* ax;
      if (p == 0) ax = (w == 0) ? (xrf + ((s >> 4) & 1) * 192 + (s & 15) * 12)
                                : (&iring[w - 1][s & (IRS - 1)][0]);
      else        ax = &hloc[w][rb][(pc == 0 ? 0 : pc - 1) * 12];
      const float* ah = &hloc[w][rb][pc * 12];

      float4 xA = ((const float4*)ax)[0], xB = ((const float4*)ax)[1], xC = ((const float4*)ax)[2];
      float4 hA = ((const float4*)ah)[0], hB = ((const float4*)ah)[1], hC = ((const float4*)ah)[2];
      float xv[12] = {xA.x,xA.y,xA.z,xA.w, xB.x,xB.y,xB.z,xB.w, xC.x,xC.y,xC.z,xC.w};
      float hv[12] = {hA.x,hA.y,hA.z,hA.w, hB.x,hB.y,hB.z,hB.w, hC.x,hC.y,hC.z,hC.w};

      // ---- gates: 4 independent 12-deep pk-FMA chains, then combine ----
      v2f axif = (v2f){0.f,0.f}, axgo = (v2f){0.f,0.f};
      v2f ahif = b_if, ahgo = b_go;
#pragma unroll
      for (int k = 0; k < 12; ++k) {
        v2f xx = { xv[k], xv[k] };
        axif = __builtin_elementwise_fma(wx_if[k], xx, axif);
        axgo = __builtin_elementwise_fma(wx_go[k], xx, axgo);
      }
#pragma unroll
      for (int k = 0; k < 12; ++k) {
        v2f hh = { hv[k], hv[k] };
        ahif = __builtin_elementwise_fma(wh_if[k], hh, ahif);
        ahgo = __builtin_elementwise_fma(wh_go[k], hh, ahgo);
      }
      v2f aif = axif + ahif, ago = axgo + ahgo;
      float ig = fast_sig(aif.x);
      float fg = fast_sig(aif.y);
      float gg = fast_tanh(ago.x);
      float og = fast_sig(ago.y);

      if (run) {
        cst = fg * cst + ig * gg;
        float hn = og * fast_tanh(cst);
        hloc[w][wb][p * 12 + j] = hn;
        if (p == 4) {
          if (w < 5) iring[w][t & (IRS - 1)][j] = hn;
          else if (seg < 3) oring[t & 15][j] = hn;
        }
        if (t == TT - 1) hfin[l * 768 + c * 12 + j] = hn;
      }

      // ---- tailer: flush a completed 16-step batch to the L3 ring ----
      if (is_tailer) {
        const int t4 = s - 4;
        if (t4 >= 0 && t4 < TT && (((t4 & 15) == 15) || t4 == TT - 1)) {
          const int m4 = t4 >> 4;
          if (kcons < m4 - (RB - 1) + 1)
            kcons = poll_ge_ag(&cons[hop_out], m4 - RB + 1, kcons);
          const float* orf = &oring[0][0];
          float o0 = orf[f0], o1 = orf[f1], o2 = orf[f2];
          float* d = rout + (m4 & (RB - 1)) * 192;
          __hip_atomic_store(d + f0, o0, __ATOMIC_RELAXED, __HIP_MEMORY_SCOPE_AGENT);
          __hip_atomic_store(d + f1, o1, __ATOMIC_RELAXED, __HIP_MEMORY_SCOPE_AGENT);
          __hip_atomic_store(d + f2, o2, __ATOMIC_RELAXED, __HIP_MEMORY_SCOPE_AGENT);
          if (lane == 0)   // release: drains this wave's stores, others keep running
            __hip_atomic_store(&prog[hop_out], m4 + 1, __ATOMIC_RELEASE, __HIP_MEMORY_SCOPE_AGENT);
        }
      }

      // ---- flag posts every 4 steps ----
      if ((u & 3) == 3 && lane == 0) {
        if (w < 5)
          __hip_atomic_store(&pflag[w], s - 3, __ATOMIC_RELEASE, __HIP_MEMORY_SCOPE_WORKGROUP);
        if (w > 0)
          __hip_atomic_store(&cflag[w], s + 1, __ATOMIC_RELEASE, __HIP_MEMORY_SCOPE_WORKGROUP);
      }
    }
  }

  // ---- epilogue: unblock any remaining pollers ----
  if (lane == 0) {
    if (w < 5) __hip_atomic_store(&pflag[w], BIGF, __ATOMIC_RELEASE, __HIP_MEMORY_SCOPE_WORKGROUP);
    if (w > 0) __hip_atomic_store(&cflag[w], BIGF, __ATOMIC_RELEASE, __HIP_MEMORY_SCOPE_WORKGROUP);
    if (is_feeder && seg > 0)
      __hip_atomic_store(&cons[hop_in], BIGF, __ATOMIC_RELAXED, __HIP_MEMORY_SCOPE_AGENT);
  }
}

// ---------------- head: lin1+relu, lin2+relu, mu, softplus(sigma) ----------------
__global__ void k_head(const float* __restrict__ hfin,
                       const float* __restrict__ w1, const float* __restrict__ b1,
                       const float* __restrict__ w2, const float* __restrict__ b2,
                       const float* __restrict__ wm, const float* __restrict__ bm,
                       const float* __restrict__ wsg, const float* __restrict__ bsg,
                       float* __restrict__ out)
{
  const int tid = threadIdx.x;
  __shared__ float s1[144], s2[144], sm[144], ss[144];
  __shared__ float v1[12], v2[12], vm[12], vs[12];
  if (tid < 144) { s1[tid] = w1[tid]; s2[tid] = w2[tid]; sm[tid] = wm[tid]; ss[tid] = wsg[tid]; }
  if (tid < 12)  { v1[tid] = b1[tid]; v2[tid] = b2[tid]; vm[tid] = bm[tid]; vs[tid] = bsg[tid]; }
  __syncthreads();
  const int r = blockIdx.x * 256 + tid;   // 0..7679 = b*120 + l
  const int b = r / 120, l = r - b * 120;
  float h[12];
#pragma unroll
  for (int k = 0; k < 12; ++k) h[k] = hfin[l * 768 + b * 12 + k];
  float u1[12];
#pragma unroll
  for (int u = 0; u < 12; ++u) {
    float a = v1[u];
#pragma unroll
    for (int k = 0; k < 12; ++k) a += s1[u * 12 + k] * h[k];
    u1[u] = fmaxf(a, 0.f);
  }
  float u2[12];
#pragma unroll
  for (int u = 0; u < 12; ++u) {
    float a = v2[u];
#pragma unroll
    for (int k = 0; k < 12; ++k) a += s2[u * 12 + k] * u1[k];
    u2[u] = fmaxf(a, 0.f);
  }
  const size_t base = (size_t)r * 12;
#pragma unroll
  for (int u = 0; u < 12; ++u) out[base + u] = u2[u];
#pragma unroll
  for (int u = 0; u < 12; ++u) {
    float a = vm[u];
#pragma unroll
    for (int k = 0; k < 12; ++k) a += sm[u * 12 + k] * u2[k];
    out[92160 + base + u] = a;
  }
#pragma unroll
  for (int u = 0; u < 12; ++u) {
    float a = vs[u];
#pragma unroll
    for (int k = 0; k < 12; ++k) a += ss[u * 12 + k] * u2[k];
    out[184320 + base + u] = fmaxf(a, 0.f) + log1pf(expf(-fabsf(a)));
  }
}

// ---------------- launcher ----------------
extern "C" void kernel_launch(void* const* d_in, const int* in_sizes, int n_in,
                              void* d_out, int out_size, void* d_ws, size_t ws_size,
                              hipStream_t stream)
{
  const float* x   = (const float*)d_in[0];
  const float* c1w = (const float*)d_in[1];
  const float* c1b = (const float*)d_in[2];
  const float* g1  = (const float*)d_in[3];
  const float* be1 = (const float*)d_in[4];
  const float* c2w = (const float*)d_in[5];
  const float* c2b = (const float*)d_in[6];
  const float* g2  = (const float*)d_in[7];
  const float* be2 = (const float*)d_in[8];
  const float* aw  = (const float*)d_in[9];
  const float* ab  = (const float*)d_in[10];
  const float* wih = (const float*)d_in[11];
  const float* whh = (const float*)d_in[12];
  const float* bih = (const float*)d_in[13];
  const float* bhh = (const float*)d_in[14];
  const float* l1w = (const float*)d_in[15];
  const float* l1b = (const float*)d_in[16];
  const float* l2w = (const float*)d_in[17];
  const float* l2b = (const float*)d_in[18];
  const float* muw = (const float*)d_in[19];
  const float* mub = (const float*)d_in[20];
  const float* sgw = (const float*)d_in[21];
  const float* sgb = (const float*)d_in[22];

  float* ws    = (float*)d_ws;
  float* stat1 = ws;                    // 12
  float* stat2 = ws + 12;               // 12
  float* aff1  = ws + 24;               // 12
  float* aff2  = ws + 36;               // 12
  int*   prog  = (int*)(ws + 64);       // 192 used
  int*   cons  = (int*)(ws + 304);      // 192 used
  float* y1    = ws + 576;              // 64*6*1020
  float* y2    = y1 + 391680;           // 64*6*1016
  float* seq0  = y2 + 390144;           // 1016*768
  float* ring  = seq0 + 780288;         // 192 hops * 8 batches * 192 floats
  float* hfin  = ring + (size_t)192 * RB * 192;   // 120*768

  hipMemsetAsync(d_ws, 0, 576 * sizeof(float), stream);  // zero stats + flags

  k_conv<<<384, 256, 0, stream>>>(x, c1w, c1b, nullptr, y1, stat1, 1024, 1020, 0);
  k_finalize<<<1, 64, 0, stream>>>(stat1, g1, be1, aff1, 1.f / 65280.f);
  k_conv<<<384, 256, 0, stream>>>(y1, c2w, c2b, aff1, y2, stat2, 1020, 1016, 1);
  k_finalize<<<1, 64, 0, stream>>>(stat2, g2, be2, aff2, 1.f / 65024.f);
  k_attn<<<1016, 768, 0, stream>>>(y2, aff2, aw, ab, seq0);
  k_lstm<<<256, TPB, 0, stream>>>(wih, whh, bih, bhh, seq0, ring, prog, cons, hfin);
  k_head<<<30, 256, 0, stream>>>(hfin, l1w, l1b, l2w, l2b, muw, mub, sgw, sgb, (float*)d_out);
}

// Round 5
// 811.232 us; speedup vs baseline: 6.0299x; 1.0559x over previous
//
#include <hip/hip_runtime.h>
#include <math.h>

// ---------------- problem constants ----------------
#define NLAY 120         // LSTM layers
#define TT   1016        // LSTM time steps (1024 - 4 - 4)
#define NB   64          // batches of 16 steps (64*16 = 1024 >= TT+4)
#define RB   8           // L3 ring depth in batches (power of 2)
#define IRS  32          // intra-block inter-wave LDS ring slots (power of 2)
#define TPB  384         // 6 waves x 64 lanes; wave = 5 layers x 12 hidden (lanes 60-63 idle)
#define BIGF (1 << 20)

typedef float v2f __attribute__((ext_vector_type(2)));

__device__ __forceinline__ float fast_rcp(float x) { return __builtin_amdgcn_rcpf(x); }
__device__ __forceinline__ float fast_sig(float x) { return fast_rcp(1.f + __expf(-x)); }
__device__ __forceinline__ float fast_tanh(float x) { return 1.f - 2.f * fast_rcp(1.f + __expf(2.f * x)); }

// agent-scope relaxed poll (global flags); s_sleep on miss; watchdog fails loud, never hangs
__device__ __forceinline__ int poll_ge_ag(const int* p, int tgt, int cur) {
  long g = 0;
  while (cur < tgt) {
    cur = __hip_atomic_load(p, __ATOMIC_RELAXED, __HIP_MEMORY_SCOPE_AGENT);
    if (cur >= tgt) break;
    __builtin_amdgcn_s_sleep(1);
    if (++g > 400000L) break;
  }
  return cur;
}
// workgroup-scope relaxed poll on an LDS flag (ds_read spin)
__device__ __forceinline__ int poll_ge_wg(const int* p, int tgt, int cur) {
  long g = 0;
  while (cur < tgt) {
    cur = __hip_atomic_load(p, __ATOMIC_RELAXED, __HIP_MEMORY_SCOPE_WORKGROUP);
    if (cur >= tgt) break;
    __builtin_amdgcn_s_sleep(1);
    if (++g > 400000L) break;
  }
  return cur;
}

// ---------------- conv1d(6->6,K=5,valid) + bias, accumulate BN stats ----------------
__global__ void k_conv(const float* __restrict__ xin, const float* __restrict__ cw,
                       const float* __restrict__ cb, const float* __restrict__ aff,
                       float* __restrict__ yout, float* __restrict__ stat,
                       int Tin, int Tout, int use_aff)
{
  const int bx = blockIdx.x;            // 0..383 : b*6+co
  const int b = bx / 6, co = bx - b * 6;
  const int tid = threadIdx.x;          // 256
  __shared__ float wsh[30];
  __shared__ float ssh[6], shsh[6];
  if (tid < 30) wsh[tid] = cw[co * 30 + tid];
  if (tid < 6) {
    ssh[tid]  = use_aff ? aff[tid] : 1.f;
    shsh[tid] = use_aff ? aff[6 + tid] : 0.f;
  }
  __syncthreads();
  const float bias = cb[co];
  float lsum = 0.f, lsq = 0.f;
  for (int t = tid; t < Tout; t += 256) {
    float acc = bias;
#pragma unroll
    for (int ci = 0; ci < 6; ++ci) {
      const float* xr = xin + ((size_t)b * 6 + ci) * Tin + t;
      const float s = ssh[ci], sh = shsh[ci];
#pragma unroll
      for (int k = 0; k < 5; ++k) {
        float v = xr[k];
        if (use_aff) v = fmaxf(fmaf(s, v, sh), 0.f);
        acc += wsh[ci * 5 + k] * v;
      }
    }
    yout[((size_t)b * 6 + co) * Tout + t] = acc;
    lsum += acc; lsq += acc * acc;
  }
  __shared__ float rs[256], rq[256];
  rs[tid] = lsum; rq[tid] = lsq;
  __syncthreads();
  for (int s = 128; s > 0; s >>= 1) {
    if (tid < s) { rs[tid] += rs[tid + s]; rq[tid] += rq[tid + s]; }
    __syncthreads();
  }
  if (tid == 0) { atomicAdd(&stat[co], rs[0]); atomicAdd(&stat[6 + co], rq[0]); }
}

// ---------------- finalize BN: stats -> per-channel scale/shift ----------------
__global__ void k_finalize(const float* __restrict__ stat,
                           const float* __restrict__ gamma, const float* __restrict__ beta,
                           float* __restrict__ aff, float invN)
{
  const int c = threadIdx.x;
  if (c < 6) {
    float mean = stat[c] * invN;
    float var  = stat[6 + c] * invN - mean * mean;
    float sc   = gamma[c] * rsqrtf(var + 1e-5f);
    aff[c]     = sc;
    aff[6 + c] = fmaf(-mean, sc, beta[c]);
  }
}

// ---------------- BN2+ReLU + attn projection (6->12) + ReLU; write seq0[t][b*12+j] ----------------
__global__ void k_attn(const float* __restrict__ y2, const float* __restrict__ aff2,
                       const float* __restrict__ aw, const float* __restrict__ ab,
                       float* __restrict__ seq0)
{
  const int t = blockIdx.x;             // 0..1015
  const int tid = threadIdx.x;          // 0..767
  __shared__ float zb[6 * 64];
  if (tid < 384) {
    const int c = tid >> 6, bb = tid & 63;
    float v = y2[((size_t)bb * 6 + c) * TT + t];
    zb[c * 64 + bb] = fmaxf(fmaf(aff2[c], v, aff2[6 + c]), 0.f);
  }
  __syncthreads();
  const int b = tid / 12, j = tid - b * 12;
  float acc = ab[j];
#pragma unroll
  for (int c = 0; c < 6; ++c) acc += aw[j * 6 + c] * zb[c * 64 + b];
  seq0[(size_t)t * 768 + tid] = fmaxf(acc, 0.f);
}

// ---------------- 120-layer LSTM: free-running waves, relaxed LDS flag protocol ----------------
// grid = 256 blocks: bid = chain*4 + seg. Wave w = 5-layer stage; lane (p,j) = layer w*5+p.
// Diagonal: at step s, group p computes t = s - p.
// Intra-wave hand-off: hloc (padded to 64 so idle lanes write a pad slot, no exec masking).
// Wave->wave: iring + RELAXED LDS flags (per-wave in-order DS pipe gives data->flag order;
// asm memory fences stop compiler motion). NO vmcnt/lgkm drains in the hot loop.
// Block->block: 16-step batches via L3 ring; only the tailer's prog post is RELEASE.
__global__ __launch_bounds__(TPB, 2) void k_lstm(
    const float* __restrict__ wih, const float* __restrict__ whh,
    const float* __restrict__ bih, const float* __restrict__ bhh,
    const float* __restrict__ seq0, float* __restrict__ ring,
    int* __restrict__ prog, int* __restrict__ cons,
    float* __restrict__ hfin)
{
  const int bid  = blockIdx.x;         // 0..255
  const int c    = bid >> 2;           // chain = batch element
  const int seg  = bid & 3;
  const int tid  = threadIdx.x;
  const int w    = tid >> 6;           // wave 0..5
  const int lane = tid & 63;
  const int p    = lane / 12;          // 0..5 (5 = pad group)
  const int j    = lane - p * 12;
  const bool act = (p < 5);
  const int pc   = act ? p : 0;        // clamped for safe addressing
  const int l    = seg * 30 + w * 5 + pc;

  // ---- LDS ----
  __shared__ __align__(16) float hloc[6][2][64];        // per-wave double buffer (+pad slots 60..63)
  __shared__ __align__(16) float iring[5][IRS][12];     // wave w -> w+1
  __shared__ __align__(16) float xring[2][16][12];      // feeder input (wave 0 private)
  __shared__ __align__(16) float oring[16][12];         // tailer staging (wave 5 private)
  __shared__ int pflag[6];                              // produced-count, posted by wave w (w<5)
  __shared__ int cflag[8];                              // consumed-count, posted by wave w (w>0)
  float* xrf = &xring[0][0][0];

  if (tid < 6) pflag[tid] = 0;
  if (tid < 8) cflag[tid] = 0;
  hloc[w][0][lane] = 0.f; hloc[w][1][lane] = 0.f;
  __syncthreads();   // ONE barrier, before the main loop only

  // ---- gate weights as (i,f),(g,o) float2 pairs -> v_pk_fma_f32 ----
  v2f wx_if[12], wx_go[12], wh_if[12], wh_go[12];
  v2f b_if = (v2f){0.f, 0.f}, b_go = (v2f){0.f, 0.f};
  if (act) {
    const float* wi = wih + l * 576;
    const float* wh = whh + l * 576;
#pragma unroll
    for (int k = 0; k < 12; ++k) {
      wx_if[k] = (v2f){ wi[(j     ) * 12 + k], wi[(j + 12) * 12 + k] };
      wx_go[k] = (v2f){ wi[(j + 24) * 12 + k], wi[(j + 36) * 12 + k] };
      wh_if[k] = (v2f){ wh[(j     ) * 12 + k], wh[(j + 12) * 12 + k] };
      wh_go[k] = (v2f){ wh[(j + 24) * 12 + k], wh[(j + 36) * 12 + k] };
    }
    const float* ba = bih + l * 48;
    const float* bb = bhh + l * 48;
    b_if = (v2f){ ba[j]      + bb[j],      ba[j + 12] + bb[j + 12] };
    b_go = (v2f){ ba[j + 24] + bb[j + 24], ba[j + 36] + bb[j + 36] };
  }

  // ---- feeder / tailer plumbing ----
  const int hop_in  = c * 3 + seg - 1;                 // valid if seg>0
  const int hop_out = c * 3 + seg;                     // valid if seg<3
  const float* rin  = ring + (size_t)((seg > 0) ? hop_in : 0) * (RB * 192);
  float*       rout = ring + (size_t)((seg < 3) ? hop_out : 0) * (RB * 192);
  const bool is_feeder = (w == 0);
  const bool is_tailer = (w == 5) && (seg < 3);

  const int f0 = lane, f1 = lane + 64, f2 = lane + 128;   // cooperative 192-float copy
  const int s0o0 = (f0 / 12) * 768 + (f0 % 12);           // seq0 gather offsets
  const int s0o1 = (f1 / 12) * 768 + (f1 % 12);
  const int s0o2 = (f2 / 12) * 768 + (f2 % 12);

  auto ld_batch = [&](int m, float* d) {
    if (seg == 0) {
      const float* b = seq0 + (size_t)m * 16 * 768 + c * 12;
      d[0] = b[s0o0]; d[1] = b[s0o1]; d[2] = b[s0o2];
    } else {
      const float* b = rin + (m & (RB - 1)) * 192;
      d[0] = __hip_atomic_load(b + f0, __ATOMIC_RELAXED, __HIP_MEMORY_SCOPE_AGENT);
      d[1] = __hip_atomic_load(b + f1, __ATOMIC_RELAXED, __HIP_MEMORY_SCOPE_AGENT);
      d[2] = __hip_atomic_load(b + f2, __ATOMIC_RELAXED, __HIP_MEMORY_SCOPE_AGENT);
    }
  };

  float pend[3] = {0.f, 0.f, 0.f};
  int kp = 0, kcons = 0;
  if (is_feeder) {
    if (seg > 0) kp = poll_ge_ag(&prog[hop_in], 2, 0);
    float cur[3];
    ld_batch(0, cur);
    ld_batch(1, pend);
    xrf[f0] = cur[0]; xrf[f1] = cur[1]; xrf[f2] = cur[2];   // batch 0 -> buffer 0
  }

  float cst = 0.f;
  int pcache = 0, ccache = 0;

  // ---- one LSTM step; `guard` constant-folds per call site ----
  auto step = [&](int s, bool guard) __attribute__((always_inline)) {
    const int t  = s - pc;
    const int rb = (s & 1) ^ 1, wb = s & 1;

    const float* ax;
    if (p == 0) ax = (w == 0) ? (xrf + ((s >> 4) & 1) * 192 + (s & 15) * 12)
                              : (&iring[w - 1][s & (IRS - 1)][0]);
    else        ax = &hloc[w][rb][(pc == 0 ? 0 : pc - 1) * 12];
    const float* ah = &hloc[w][rb][pc * 12];

    float4 xA = ((const float4*)ax)[0], xB = ((const float4*)ax)[1], xC = ((const float4*)ax)[2];
    float4 hA = ((const float4*)ah)[0], hB = ((const float4*)ah)[1], hC = ((const float4*)ah)[2];
    float xv[12] = {xA.x,xA.y,xA.z,xA.w, xB.x,xB.y,xB.z,xB.w, xC.x,xC.y,xC.z,xC.w};
    float hv[12] = {hA.x,hA.y,hA.z,hA.w, hB.x,hB.y,hB.z,hB.w, hC.x,hC.y,hC.z,hC.w};

    v2f axif = (v2f){0.f,0.f}, axgo = (v2f){0.f,0.f};
    v2f ahif = b_if, ahgo = b_go;
#pragma unroll
    for (int k = 0; k < 12; ++k) {
      v2f xx = { xv[k], xv[k] };
      axif = __builtin_elementwise_fma(wx_if[k], xx, axif);
      axgo = __builtin_elementwise_fma(wx_go[k], xx, axgo);
    }
#pragma unroll
    for (int k = 0; k < 12; ++k) {
      v2f hh = { hv[k], hv[k] };
      ahif = __builtin_elementwise_fma(wh_if[k], hh, ahif);
      ahgo = __builtin_elementwise_fma(wh_go[k], hh, ahgo);
    }
    v2f aif = axif + ahif, ago = axgo + ahgo;
    float ig = fast_sig(aif.x);
    float fg = fast_sig(aif.y);
    float gg = fast_tanh(ago.x);
    float og = fast_sig(ago.y);

    if (!guard) {
      // steady region: all t valid; idle lanes write their pad slot
      cst = fg * cst + ig * gg;
      float hn = og * fast_tanh(cst);
      hloc[w][wb][p * 12 + j] = hn;
      if (p == 4) {
        if (w < 5) iring[w][t & (IRS - 1)][j] = hn;
        else if (seg < 3) oring[t & 15][j] = hn;
      }
    } else {
      const bool run = act && (t >= 0) && (t < TT);
      if (run) {
        cst = fg * cst + ig * gg;
        float hn = og * fast_tanh(cst);
        hloc[w][wb][p * 12 + j] = hn;
        if (p == 4) {
          if (w < 5) iring[w][t & (IRS - 1)][j] = hn;
          else if (seg < 3) oring[t & 15][j] = hn;
        }
        if (t == TT - 1) hfin[l * 768 + c * 12 + j] = hn;
      }
    }

    // tailer: flush a completed 16-step batch to the L3 ring (wave-uniform branch)
    if (is_tailer) {
      const int t4 = s - 4;
      if (t4 >= 0 && t4 < TT && (((t4 & 15) == 15) || t4 == TT - 1)) {
        const int m4 = t4 >> 4;
        if (kcons < m4 - (RB - 1) + 1)
          kcons = poll_ge_ag(&cons[hop_out], m4 - RB + 1, kcons);
        const float* orf = &oring[0][0];
        float o0 = orf[f0], o1 = orf[f1], o2 = orf[f2];
        float* d = rout + (m4 & (RB - 1)) * 192;
        __hip_atomic_store(d + f0, o0, __ATOMIC_RELAXED, __HIP_MEMORY_SCOPE_AGENT);
        __hip_atomic_store(d + f1, o1, __ATOMIC_RELAXED, __HIP_MEMORY_SCOPE_AGENT);
        __hip_atomic_store(d + f2, o2, __ATOMIC_RELAXED, __HIP_MEMORY_SCOPE_AGENT);
        if (lane == 0)   // RELEASE: drains this wave's 3 stores; other waves keep running
          __hip_atomic_store(&prog[hop_out], m4 + 1, __ATOMIC_RELEASE, __HIP_MEMORY_SCOPE_AGENT);
      }
    }
  };

  for (int s4 = 0; s4 < 1024; s4 += 4) {
    // ---- batch boundary: feeder publishes batch m+1, starts loads for m+2 ----
    if (is_feeder && (s4 & 15) == 0) {
      const int m = s4 >> 4;
      if (m + 1 < NB) {
        float* xd = xrf + ((m + 1) & 1) * 192;
        xd[f0] = pend[0]; xd[f1] = pend[1]; xd[f2] = pend[2];
      }
      if (m + 2 < NB) {
        if (seg > 0 && kp < m + 3) kp = poll_ge_ag(&prog[hop_in], m + 3, kp);
        ld_batch(m + 2, pend);     // stays in flight for the next 16 steps (no drains now)
      }
      if (seg > 0 && lane == 0)
        __hip_atomic_store(&cons[hop_in], m, __ATOMIC_RELAXED, __HIP_MEMORY_SCOPE_AGENT);
    }

    // ---- relaxed LDS flag checks, once per 4 steps ----
    if (w > 0 && s4 < TT) {
      const int tgt = (s4 + 4 < TT) ? (s4 + 4) : TT;
      if (pcache < tgt) {
        pcache = poll_ge_wg(&pflag[w - 1], tgt, pcache);
        asm volatile("" ::: "memory");
      }
    }
    if (w < 5 && s4 >= 36) {
      const int tgt = s4 - 32;
      if (ccache < tgt) {
        ccache = poll_ge_wg(&cflag[w + 1], tgt, ccache);
        asm volatile("" ::: "memory");
      }
    }

    if (s4 >= 4 && s4 < 1012) {
      step(s4 + 0, false); step(s4 + 1, false); step(s4 + 2, false); step(s4 + 3, false);
    } else {
      step(s4 + 0, true);  step(s4 + 1, true);  step(s4 + 2, true);  step(s4 + 3, true);
    }

    // ---- relaxed flag posts (DS pipe in-order per wave orders data before flag) ----
    if (lane == 0) {
      asm volatile("" ::: "memory");
      if (w < 5)
        __hip_atomic_store(&pflag[w], s4, __ATOMIC_RELAXED, __HIP_MEMORY_SCOPE_WORKGROUP);
      if (w > 0 && s4 + 3 < TT)
        __hip_atomic_store(&cflag[w], s4 + 4, __ATOMIC_RELAXED, __HIP_MEMORY_SCOPE_WORKGROUP);
    }
  }

  // ---- epilogue: unblock any remaining pollers ----
  if (lane == 0) {
    asm volatile("" ::: "memory");
    if (w < 5) __hip_atomic_store(&pflag[w], BIGF, __ATOMIC_RELAXED, __HIP_MEMORY_SCOPE_WORKGROUP);
    if (w > 0) __hip_atomic_store(&cflag[w], BIGF, __ATOMIC_RELAXED, __HIP_MEMORY_SCOPE_WORKGROUP);
    if (is_feeder && seg > 0)
      __hip_atomic_store(&cons[hop_in], BIGF, __ATOMIC_RELAXED, __HIP_MEMORY_SCOPE_AGENT);
  }
}

// ---------------- head: lin1+relu, lin2+relu, mu, softplus(sigma) ----------------
__global__ void k_head(const float* __restrict__ hfin,
                       const float* __restrict__ w1, const float* __restrict__ b1,
                       const float* __restrict__ w2, const float* __restrict__ b2,
                       const float* __restrict__ wm, const float* __restrict__ bm,
                       const float* __restrict__ wsg, const float* __restrict__ bsg,
                       float* __restrict__ out)
{
  const int tid = threadIdx.x;
  __shared__ float s1[144], s2[144], sm[144], ss[144];
  __shared__ float v1[12], v2[12], vm[12], vs[12];
  if (tid < 144) { s1[tid] = w1[tid]; s2[tid] = w2[tid]; sm[tid] = wm[tid]; ss[tid] = wsg[tid]; }
  if (tid < 12)  { v1[tid] = b1[tid]; v2[tid] = b2[tid]; vm[tid] = bm[tid]; vs[tid] = bsg[tid]; }
  __syncthreads();
  const int r = blockIdx.x * 256 + tid;   // 0..7679 = b*120 + l
  const int b = r / 120, l = r - b * 120;
  float h[12];
#pragma unroll
  for (int k = 0; k < 12; ++k) h[k] = hfin[l * 768 + b * 12 + k];
  float u1[12];
#pragma unroll
  for (int u = 0; u < 12; ++u) {
    float a = v1[u];
#pragma unroll
    for (int k = 0; k < 12; ++k) a += s1[u * 12 + k] * h[k];
    u1[u] = fmaxf(a, 0.f);
  }
  float u2[12];
#pragma unroll
  for (int u = 0; u < 12; ++u) {
    float a = v2[u];
#pragma unroll
    for (int k = 0; k < 12; ++k) a += s2[u * 12 + k] * u1[k];
    u2[u] = fmaxf(a, 0.f);
  }
  const size_t base = (size_t)r * 12;
#pragma unroll
  for (int u = 0; u < 12; ++u) out[base + u] = u2[u];
#pragma unroll
  for (int u = 0; u < 12; ++u) {
    float a = vm[u];
#pragma unroll
    for (int k = 0; k < 12; ++k) a += sm[u * 12 + k] * u2[k];
    out[92160 + base + u] = a;
  }
#pragma unroll
  for (int u = 0; u < 12; ++u) {
    float a = vs[u];
#pragma unroll
    for (int k = 0; k < 12; ++k) a += ss[u * 12 + k] * u2[k];
    out[184320 + base + u] = fmaxf(a, 0.f) + log1pf(expf(-fabsf(a)));
  }
}

// ---------------- launcher ----------------
extern "C" void kernel_launch(void* const* d_in, const int* in_sizes, int n_in,
                              void* d_out, int out_size, void* d_ws, size_t ws_size,
                              hipStream_t stream)
{
  const float* x   = (const float*)d_in[0];
  const float* c1w = (const float*)d_in[1];
  const float* c1b = (const float*)d_in[2];
  const float* g1  = (const float*)d_in[3];
  const float* be1 = (const float*)d_in[4];
  const float* c2w = (const float*)d_in[5];
  const float* c2b = (const float*)d_in[6];
  const float* g2  = (const float*)d_in[7];
  const float* be2 = (const float*)d_in[8];
  const float* aw  = (const float*)d_in[9];
  const float* ab  = (const float*)d_in[10];
  const float* wih = (const float*)d_in[11];
  const float* whh = (const float*)d_in[12];
  const float* bih = (const float*)d_in[13];
  const float* bhh = (const float*)d_in[14];
  const float* l1w = (const float*)d_in[15];
  const float* l1b = (const float*)d_in[16];
  const float* l2w = (const float*)d_in[17];
  const float* l2b = (const float*)d_in[18];
  const float* muw = (const float*)d_in[19];
  const float* mub = (const float*)d_in[20];
  const float* sgw = (const float*)d_in[21];
  const float* sgb = (const float*)d_in[22];

  float* ws    = (float*)d_ws;
  float* stat1 = ws;                    // 12
  float* stat2 = ws + 12;               // 12
  float* aff1  = ws + 24;               // 12
  float* aff2  = ws + 36;               // 12
  int*   prog  = (int*)(ws + 64);       // 192 used
  int*   cons  = (int*)(ws + 304);      // 192 used
  float* y1    = ws + 576;              // 64*6*1020
  float* y2    = y1 + 391680;           // 64*6*1016
  float* seq0  = y2 + 390144;           // 1016*768
  float* ring  = seq0 + 780288;         // 192 hops * 8 batches * 192 floats
  float* hfin  = ring + (size_t)192 * RB * 192;   // 120*768

  hipMemsetAsync(d_ws, 0, 576 * sizeof(float), stream);  // zero stats + flags

  k_conv<<<384, 256, 0, stream>>>(x, c1w, c1b, nullptr, y1, stat1, 1024, 1020, 0);
  k_finalize<<<1, 64, 0, stream>>>(stat1, g1, be1, aff1, 1.f / 65280.f);
  k_conv<<<384, 256, 0, stream>>>(y1, c2w, c2b, aff1, y2, stat2, 1020, 1016, 1);
  k_finalize<<<1, 64, 0, stream>>>(stat2, g2, be2, aff2, 1.f / 65024.f);
  k_attn<<<1016, 768, 0, stream>>>(y2, aff2, aw, ab, seq0);
  k_lstm<<<256, TPB, 0, stream>>>(wih, whh, bih, bhh, seq0, ring, prog, cons, hfin);
  k_head<<<30, 256, 0, stream>>>(hfin, l1w, l1b, l2w, l2b, muw, mub, sgw, sgb, (float*)d_out);
}